// Round 1
// baseline (1728.666 us; speedup 1.0000x reference)
//
#include <hip/hip_runtime.h>
#include <cstdint>

using u16 = unsigned short;
using u32 = unsigned int;
typedef __bf16  bf16x8 __attribute__((ext_vector_type(8)));
typedef float   f32x4  __attribute__((ext_vector_type(4)));

__device__ __forceinline__ u16 f2b(float x) {
    u32 u = __builtin_bit_cast(u32, x);
    u = (u + 0x7fffu + ((u >> 16) & 1u)) >> 16;
    return (u16)u;
}

__device__ __forceinline__ f32x4 mfma16(bf16x8 a, bf16x8 b, f32x4 c) {
    return __builtin_amdgcn_mfma_f32_16x16x32_bf16(a, b, c, 0, 0, 0);
}

__device__ __forceinline__ void gload16(const void* g, void* lds) {
    auto gp = (__attribute__((address_space(1))) void*)(uintptr_t)g;
    auto lp = (__attribute__((address_space(3))) void*)(uintptr_t)lds;
    __builtin_amdgcn_global_load_lds(gp, lp, 16, 0, 0);
}

// ---------------------------------------------------------------------------
// GEMM: A [M,K] bf16 row-major, Bt [N,K] bf16 row-major (weights pre-transposed)
// C = A*B (+bias) (+gelu) (+resid). 128x128 tile, BK=32, 4 waves (2x2 of 64x64).
// EPI: 0 = bias->bf16, 1 = bias+gelu->bf16, 2 = bias + f32 resid +=, 3 = plain f32
// ---------------------------------------------------------------------------
template <int EPI>
__device__ __forceinline__ void gemm_body(
    const u16* __restrict__ A, const u16* __restrict__ Bt,
    const float* __restrict__ bias,
    float* __restrict__ outf, u16* __restrict__ outb,
    int M, int N, int K, int bm, int bn)
{
    __shared__ u16 lsA[128 * 32];
    __shared__ u16 lsB[128 * 32];
    const int tid  = threadIdx.x;
    const int w    = tid >> 6, lane = tid & 63;
    const int lr   = lane & 15, lg = lane >> 4;
    const int m0   = bm * 128, n0 = bn * 128;
    const int wr   = (w >> 1) * 64, wc = (w & 1) * 64;
    f32x4 acc[4][4] = {};

    const int row0 = tid >> 2;
    const int kp   = (tid & 3) * 8;
    const u16* a0  = A  + (size_t)(m0 + row0) * K + kp;
    const u16* a1  = a0 + (size_t)64 * K;
    const u16* b0p = Bt + (size_t)(n0 + row0) * K + kp;
    const u16* b1p = b0p + (size_t)64 * K;
    char* ldsAb = (char*)lsA + w * 1024;
    char* ldsBb = (char*)lsB + w * 1024;

    const int nk = K >> 5;
    for (int kt = 0; kt < nk; ++kt) {
        const int ko = kt * 32;
        __syncthreads();                       // prev iter's LDS reads done
        gload16(a0 + ko, ldsAb);
        gload16(a1 + ko, ldsAb + 4096);
        gload16(b0p + ko, ldsBb);
        gload16(b1p + ko, ldsBb + 4096);
        __syncthreads();                       // compiler drains vmcnt before barrier
        bf16x8 af[4], bfv[4];
#pragma unroll
        for (int i = 0; i < 4; i++)
            af[i] = *(const bf16x8*)&lsA[(wr + i * 16 + lr) * 32 + lg * 8];
#pragma unroll
        for (int j = 0; j < 4; j++)
            bfv[j] = *(const bf16x8*)&lsB[(wc + j * 16 + lr) * 32 + lg * 8];
#pragma unroll
        for (int i = 0; i < 4; i++)
#pragma unroll
            for (int j = 0; j < 4; j++)
                acc[i][j] = mfma16(af[i], bfv[j], acc[i][j]);
    }

#pragma unroll
    for (int j = 0; j < 4; j++) {
        const int gc = n0 + wc + j * 16 + lr;
        float bv = 0.f;
        if constexpr (EPI != 3) bv = bias[gc];
#pragma unroll
        for (int i = 0; i < 4; i++) {
            const int grb = m0 + wr + i * 16 + lg * 4;
#pragma unroll
            for (int r = 0; r < 4; r++) {
                float v = acc[i][j][r] + bv;
                if constexpr (EPI == 1) v = 0.5f * v * (1.f + erff(v * 0.70710678118654752f));
                const size_t o = (size_t)(grb + r) * N + gc;
                if constexpr (EPI == 2)      outf[o] += v;
                else if constexpr (EPI == 3) outf[o] = v;
                else                         outb[o] = f2b(v);
            }
        }
    }
}

__global__ __launch_bounds__(256) void gemm_qkv_k(
    const u16* __restrict__ A,
    const u16* B0, const u16* B1, const u16* B2,
    const float* c0, const float* c1, const float* c2,
    u16* o0, u16* o1, u16* o2)
{
    const int z = blockIdx.z;
    gemm_body<0>(A, z == 0 ? B0 : (z == 1 ? B1 : B2),
                 z == 0 ? c0 : (z == 1 ? c1 : c2),
                 nullptr, z == 0 ? o0 : (z == 1 ? o1 : o2),
                 2048, 1024, 1024, blockIdx.y, blockIdx.x);
}
__global__ __launch_bounds__(256) void gemm_gelu_k(
    const u16* A, const u16* Bt, const float* bias, u16* out, int M, int N, int K)
{
    gemm_body<1>(A, Bt, bias, nullptr, out, M, N, K, blockIdx.y, blockIdx.x);
}
__global__ __launch_bounds__(256) void gemm_resid_k(
    const u16* A, const u16* Bt, const float* bias, float* out, int M, int N, int K)
{
    gemm_body<2>(A, Bt, bias, out, nullptr, M, N, K, blockIdx.y, blockIdx.x);
}
__global__ __launch_bounds__(256) void gemm_plain_k(
    const u16* A, const u16* Bt, float* out, int M, int N, int K)
{
    gemm_body<3>(A, Bt, nullptr, out, nullptr, M, N, K, blockIdx.y, blockIdx.x);
}

// ---------------------------------------------------------------------------
// Flash attention. q,k bf16 [T,D]; vT bf16 [D,T]; out bf16 [T,D].
// 1 wave = 16 q-rows of one head; KV tiles of 32; online softmax.
// ---------------------------------------------------------------------------
__global__ __launch_bounds__(256) void flash_attn_k(
    const u16* __restrict__ q, const u16* __restrict__ k,
    const u16* __restrict__ vT, u16* __restrict__ out)
{
    constexpr int D = 1024, T = 2048;
    __shared__ u16 pbuf[4][512];               // wave-private 16x32 P tile
    const int w = threadIdx.x >> 6, lane = threadIdx.x & 63;
    const int lr = lane & 15, lg = lane >> 4;
    const int h  = blockIdx.y;
    const int qt = (gridDim.x - 1 - blockIdx.x) * 4 + w;   // longest jobs first
    const int q0 = qt * 16;
    const int hoff = h * 64;

    const bf16x8 qf0 = *(const bf16x8*)(q + (size_t)(q0 + lr) * D + hoff + lg * 8);
    const bf16x8 qf1 = *(const bf16x8*)(q + (size_t)(q0 + lr) * D + hoff + 32 + lg * 8);

    f32x4 oa[4] = {};
    float m_r[4] = {-1e30f, -1e30f, -1e30f, -1e30f};
    float l_r[4] = {};
    u16* pb = pbuf[w];

    const int ntiles = q0 / 32 + 1;
    for (int t = 0; t < ntiles; ++t) {
        const int kv0 = t * 32;
        f32x4 s0 = {}, s1 = {};
        {
            const u16* kb = k + (size_t)(kv0 + lr) * D + hoff + lg * 8;
            s0 = mfma16(qf0, *(const bf16x8*)kb, s0);
            s0 = mfma16(qf1, *(const bf16x8*)(kb + 32), s0);
            const u16* kb1 = kb + (size_t)16 * D;
            s1 = mfma16(qf0, *(const bf16x8*)kb1, s1);
            s1 = mfma16(qf1, *(const bf16x8*)(kb1 + 32), s1);
        }
        const bool needmask = (kv0 + 31 > q0);
        float p0[4], p1[4], alpha[4];
#pragma unroll
        for (int r = 0; r < 4; r++) {
            float v0 = s0[r] * 0.125f, v1 = s1[r] * 0.125f;
            if (needmask) {
                const int rg = q0 + lg * 4 + r;
                if (kv0 + lr > rg)      v0 = -1e30f;
                if (kv0 + 16 + lr > rg) v1 = -1e30f;
            }
            float mx = fmaxf(v0, v1);
            mx = fmaxf(mx, __shfl_xor(mx, 1));
            mx = fmaxf(mx, __shfl_xor(mx, 2));
            mx = fmaxf(mx, __shfl_xor(mx, 4));
            mx = fmaxf(mx, __shfl_xor(mx, 8));
            const float mn = fmaxf(m_r[r], mx);
            alpha[r] = __expf(m_r[r] - mn);
            m_r[r] = mn;
            p0[r] = __expf(v0 - mn);
            p1[r] = __expf(v1 - mn);
            float ps = p0[r] + p1[r];
            ps += __shfl_xor(ps, 1);
            ps += __shfl_xor(ps, 2);
            ps += __shfl_xor(ps, 4);
            ps += __shfl_xor(ps, 8);
            l_r[r] = l_r[r] * alpha[r] + ps;
        }
#pragma unroll
        for (int r = 0; r < 4; r++) {
            pb[(lg * 4 + r) * 32 + lr]      = f2b(p0[r]);
            pb[(lg * 4 + r) * 32 + 16 + lr] = f2b(p1[r]);
        }
        const bf16x8 pa = *(const bf16x8*)&pb[lr * 32 + lg * 8];
#pragma unroll
        for (int n = 0; n < 4; n++) {
#pragma unroll
            for (int r = 0; r < 4; r++) oa[n][r] *= alpha[r];
        }
#pragma unroll
        for (int n = 0; n < 4; n++) {
            const bf16x8 vf = *(const bf16x8*)(vT + (size_t)(hoff + n * 16 + lr) * T + kv0 + lg * 8);
            oa[n] = mfma16(pa, vf, oa[n]);
        }
    }
#pragma unroll
    for (int n = 0; n < 4; n++)
#pragma unroll
        for (int r = 0; r < 4; r++)
            out[(size_t)(q0 + lg * 4 + r) * D + hoff + n * 16 + lr] = f2b(oa[n][r] / l_r[r]);
}

// ---------------------------------------------------------------------------
// Transpose + convert: src [K][N] f32 -> dst [N][K] bf16 (layer via blockIdx.z)
// ---------------------------------------------------------------------------
__global__ __launch_bounds__(256) void transpose_cvt_k(
    const float* __restrict__ src, u16* __restrict__ dst, int K, int N)
{
    __shared__ float tile[32][33];
    const size_t zo = (size_t)blockIdx.z * K * N;
    src += zo; dst += zo;
    const int n0 = blockIdx.x * 32, k0 = blockIdx.y * 32;
    const int tx = threadIdx.x & 31, ty = threadIdx.x >> 5;
#pragma unroll
    for (int r = 0; r < 32; r += 8)
        tile[ty + r][tx] = src[(size_t)(k0 + ty + r) * N + n0 + tx];
    __syncthreads();
#pragma unroll
    for (int r = 0; r < 32; r += 8)
        dst[(size_t)(n0 + ty + r) * K + k0 + tx] = f2b(tile[tx][ty + r]);
}

// bf16 transpose: src [R][C] -> dst [C][R]
__global__ __launch_bounds__(256) void transpose_u16_k(
    const u16* __restrict__ src, u16* __restrict__ dst, int R, int C)
{
    __shared__ u16 tile[32][33];
    const int c0 = blockIdx.x * 32, r0 = blockIdx.y * 32;
    const int tx = threadIdx.x & 31, ty = threadIdx.x >> 5;
#pragma unroll
    for (int r = 0; r < 32; r += 8)
        tile[ty + r][tx] = src[(size_t)(r0 + ty + r) * C + c0 + tx];
    __syncthreads();
#pragma unroll
    for (int r = 0; r < 32; r += 8)
        dst[(size_t)(c0 + ty + r) * R + r0 + tx] = tile[tx][ty + r];
}

// ---------------------------------------------------------------------------
// Embedding + sinusoidal positional encoding. x f32 [T,1024].
// ---------------------------------------------------------------------------
__global__ __launch_bounds__(256) void embed_pos_k(
    const int* __restrict__ idx, const float* __restrict__ emb, float* __restrict__ x)
{
    const int t = blockIdx.x, tid = threadIdx.x;
    const int tok = idx[t];
    float4 e = ((const float4*)(emb + (size_t)tok * 1024))[tid];
    const int d0 = tid * 4;
    const float c = -0.0089944730195080f;      // -ln(10000)/1024
    const float a0 = (float)t * expf((float)d0 * c);
    const float a1 = (float)t * expf((float)(d0 + 2) * c);
    e.x += sinf(a0); e.y += cosf(a0); e.z += sinf(a1); e.w += cosf(a1);
    ((float4*)(x + (size_t)t * 1024))[tid] = e;
}

// ---------------------------------------------------------------------------
// LayerNorm: x f32 [.,1024] -> out bf16. One block per row.
// ---------------------------------------------------------------------------
__global__ __launch_bounds__(256) void layernorm_k(
    const float* __restrict__ x, const float* __restrict__ g,
    const float* __restrict__ b, u16* __restrict__ out)
{
    __shared__ float red[8];
    const int row = blockIdx.x, tid = threadIdx.x;
    const int w = tid >> 6, lane = tid & 63;
    const float4 v = ((const float4*)(x + (size_t)row * 1024))[tid];
    float s = v.x + v.y + v.z + v.w;
#pragma unroll
    for (int d = 1; d < 64; d <<= 1) s += __shfl_xor(s, d);
    if (lane == 0) red[w] = s;
    __syncthreads();
    const float mu = (red[0] + red[1] + red[2] + red[3]) * (1.f / 1024.f);
    const float d0 = v.x - mu, d1 = v.y - mu, d2 = v.z - mu, d3 = v.w - mu;
    float s2 = d0 * d0 + d1 * d1 + d2 * d2 + d3 * d3;
#pragma unroll
    for (int d = 1; d < 64; d <<= 1) s2 += __shfl_xor(s2, d);
    if (lane == 0) red[4 + w] = s2;
    __syncthreads();
    const float var = (red[4] + red[5] + red[6] + red[7]) * (1.f / 1024.f);
    const float rs = rsqrtf(var + 1e-5f);
    const float4 gv = ((const float4*)g)[tid];
    const float4 bv = ((const float4*)b)[tid];
    u32 p0 = (u32)f2b(d0 * rs * gv.x + bv.x) | ((u32)f2b(d1 * rs * gv.y + bv.y) << 16);
    u32 p1 = (u32)f2b(d2 * rs * gv.z + bv.z) | ((u32)f2b(d3 * rs * gv.w + bv.w) << 16);
    ((uint2*)(out + (size_t)row * 1024))[tid] = make_uint2(p0, p1);
}

// ---------------------------------------------------------------------------
extern "C" void kernel_launch(void* const* d_in, const int* in_sizes, int n_in,
                              void* d_out, int out_size, void* d_ws, size_t ws_size,
                              hipStream_t stream)
{
    const int*   idx   = (const int*)  d_in[0];
    const float* embed = (const float*)d_in[1];
    const float* Wq    = (const float*)d_in[2];
    const float* Wk    = (const float*)d_in[3];
    const float* Wv    = (const float*)d_in[4];
    const float* Wo    = (const float*)d_in[5];
    const float* bq    = (const float*)d_in[6];
    const float* bk    = (const float*)d_in[7];
    const float* bv    = (const float*)d_in[8];
    const float* bo    = (const float*)d_in[9];
    const float* ln1g  = (const float*)d_in[10];
    const float* ln1b  = (const float*)d_in[11];
    const float* ln2g  = (const float*)d_in[12];
    const float* ln2b  = (const float*)d_in[13];
    const float* w1    = (const float*)d_in[14];
    const float* b1    = (const float*)d_in[15];
    const float* w2    = (const float*)d_in[16];
    const float* b2    = (const float*)d_in[17];
    const float* lnfg  = (const float*)d_in[18];
    const float* lnfb  = (const float*)d_in[19];
    const float* headw = (const float*)d_in[20];

    char* ws = (char*)d_ws;
    auto alloc = [&](size_t bytes) {
        char* p = ws;
        ws += (bytes + 255) & ~(size_t)255;
        return p;
    };
    u16*   WqT = (u16*)alloc((size_t)4 * 1024 * 1024 * 2);
    u16*   WkT = (u16*)alloc((size_t)4 * 1024 * 1024 * 2);
    u16*   WvT = (u16*)alloc((size_t)4 * 1024 * 1024 * 2);
    u16*   WoT = (u16*)alloc((size_t)4 * 1024 * 1024 * 2);
    u16*   w1T = (u16*)alloc((size_t)4 * 1024 * 4096 * 2);
    u16*   w2T = (u16*)alloc((size_t)4 * 1024 * 4096 * 2);
    u16*   hT  = (u16*)alloc((size_t)32000 * 1024 * 2);
    float* x   = (float*)alloc((size_t)2048 * 1024 * 4);
    u16*   hb  = (u16*)alloc((size_t)2048 * 1024 * 2);
    u16*   qb  = (u16*)alloc((size_t)2048 * 1024 * 2);
    u16*   kb  = (u16*)alloc((size_t)2048 * 1024 * 2);
    u16*   vb  = (u16*)alloc((size_t)2048 * 1024 * 2);
    u16*   vTb = (u16*)alloc((size_t)2048 * 1024 * 2);
    u16*   ab  = (u16*)alloc((size_t)2048 * 1024 * 2);
    u16*   ff  = (u16*)alloc((size_t)2048 * 4096 * 2);

    // Weight conversion + transpose (must rerun every call: no caching allowed)
    transpose_cvt_k<<<dim3(32, 32, 4),  256, 0, stream>>>(Wq, WqT, 1024, 1024);
    transpose_cvt_k<<<dim3(32, 32, 4),  256, 0, stream>>>(Wk, WkT, 1024, 1024);
    transpose_cvt_k<<<dim3(32, 32, 4),  256, 0, stream>>>(Wv, WvT, 1024, 1024);
    transpose_cvt_k<<<dim3(32, 32, 4),  256, 0, stream>>>(Wo, WoT, 1024, 1024);
    transpose_cvt_k<<<dim3(128, 32, 4), 256, 0, stream>>>(w1, w1T, 1024, 4096);
    transpose_cvt_k<<<dim3(32, 128, 4), 256, 0, stream>>>(w2, w2T, 4096, 1024);
    transpose_cvt_k<<<dim3(1000, 32, 1), 256, 0, stream>>>(headw, hT, 1024, 32000);

    embed_pos_k<<<dim3(2048), 256, 0, stream>>>(idx, embed, x);

    for (int l = 0; l < 4; ++l) {
        layernorm_k<<<dim3(2048), 256, 0, stream>>>(x, ln1g + l * 1024, ln1b + l * 1024, hb);
        gemm_qkv_k<<<dim3(8, 16, 3), 256, 0, stream>>>(hb,
            WqT + (size_t)l * 1048576, WkT + (size_t)l * 1048576, WvT + (size_t)l * 1048576,
            bq + l * 1024, bk + l * 1024, bv + l * 1024, qb, kb, vb);
        transpose_u16_k<<<dim3(32, 64), 256, 0, stream>>>(vb, vTb, 2048, 1024);
        flash_attn_k<<<dim3(32, 16), 256, 0, stream>>>(qb, kb, vTb, ab);
        gemm_resid_k<<<dim3(8, 16), 256, 0, stream>>>(ab, WoT + (size_t)l * 1048576,
                                                      bo + l * 1024, x, 2048, 1024, 1024);
        layernorm_k<<<dim3(2048), 256, 0, stream>>>(x, ln2g + l * 1024, ln2b + l * 1024, hb);
        gemm_gelu_k<<<dim3(32, 16), 256, 0, stream>>>(hb, w1T + (size_t)l * 4194304,
                                                      b1 + l * 4096, ff, 2048, 4096, 1024);
        gemm_resid_k<<<dim3(8, 16), 256, 0, stream>>>(ff, w2T + (size_t)l * 4194304,
                                                      b2 + l * 1024, x, 2048, 1024, 4096);
    }
    layernorm_k<<<dim3(2048), 256, 0, stream>>>(x, lnfg, lnfb, hb);
    gemm_plain_k<<<dim3(250, 16), 256, 0, stream>>>(hb, hT, (float*)d_out, 2048, 32000, 1024);
}

// Round 2
// 1511.582 us; speedup vs baseline: 1.1436x; 1.1436x over previous
//
#include <hip/hip_runtime.h>
#include <cstdint>

using u16 = unsigned short;
using u32 = unsigned int;
typedef __bf16  bf16x8 __attribute__((ext_vector_type(8)));
typedef float   f32x4  __attribute__((ext_vector_type(4)));

__device__ __forceinline__ u16 f2b(float x) {
    u32 u = __builtin_bit_cast(u32, x);
    u = (u + 0x7fffu + ((u >> 16) & 1u)) >> 16;
    return (u16)u;
}

__device__ __forceinline__ f32x4 mfma16(bf16x8 a, bf16x8 b, f32x4 c) {
    return __builtin_amdgcn_mfma_f32_16x16x32_bf16(a, b, c, 0, 0, 0);
}

__device__ __forceinline__ void gload16(const void* g, void* lds) {
    auto gp = (__attribute__((address_space(1))) void*)(uintptr_t)g;
    auto lp = (__attribute__((address_space(3))) void*)(uintptr_t)lds;
    __builtin_amdgcn_global_load_lds(gp, lp, 16, 0, 0);
}

// bijective XCD-aware swizzle (m204); bm fastest so co-resident blocks share B panels
__device__ __forceinline__ int2 swz_bmbn(int nbm) {
    const int nwg = gridDim.x, orig = blockIdx.x;
    const int q = nwg >> 3, r = nwg & 7;
    const int xcd = orig & 7, lin = orig >> 3;
    const int id = (xcd < r ? xcd * (q + 1) : r * (q + 1) + (xcd - r) * q) + lin;
    return make_int2(id % nbm, id / nbm);
}

// ---------------------------------------------------------------------------
// 128x128 GEMM body, BK=32, dbuf LDS, k-slot XOR swizzle (2-way conflicts).
// EPI: 1 = bias+gelu->bf16, 3 = plain f32
// ---------------------------------------------------------------------------
template <int EPI>
__device__ __forceinline__ void gemm128(
    const u16* __restrict__ A, const u16* __restrict__ Bt,
    const float* __restrict__ bias,
    float* __restrict__ outf, u16* __restrict__ outb,
    int M, int N, int K, int bm, int bn)
{
    __shared__ u16 lsA[2][128 * 32];
    __shared__ u16 lsB[2][128 * 32];
    const int tid  = threadIdx.x;
    const int w    = tid >> 6, lane = tid & 63;
    const int lr   = lane & 15, lg = lane >> 4;
    const int m0   = bm * 128, n0 = bn * 128;
    const int wr   = (w >> 1) * 64, wc = (w & 1) * 64;
    f32x4 acc[4][4] = {};

    const int row0 = tid >> 2;                                 // 0..63
    const int ksw8 = ((lane & 3) ^ ((lane >> 3) & 3)) * 8;     // swizzled src k-chunk
    const u16* a0  = A  + (size_t)(m0 + row0) * K + ksw8;
    const u16* a1  = a0 + (size_t)64 * K;
    const u16* b0p = Bt + (size_t)(n0 + row0) * K + ksw8;
    const u16* b1p = b0p + (size_t)64 * K;
    const int rsw  = (lg ^ ((lr >> 1) & 3)) * 8;               // swizzled read k-off

    auto stage = [&](int buf, int ko) {
        char* la = (char*)lsA[buf] + w * 1024;
        char* lb = (char*)lsB[buf] + w * 1024;
        gload16(a0 + ko, la);
        gload16(a1 + ko, la + 4096);
        gload16(b0p + ko, lb);
        gload16(b1p + ko, lb + 4096);
    };
    auto compute = [&](int buf) {
        bf16x8 af[4], bfv[4];
#pragma unroll
        for (int i = 0; i < 4; i++)
            af[i] = *(const bf16x8*)&lsA[buf][(wr + i * 16 + lr) * 32 + rsw];
#pragma unroll
        for (int j = 0; j < 4; j++)
            bfv[j] = *(const bf16x8*)&lsB[buf][(wc + j * 16 + lr) * 32 + rsw];
#pragma unroll
        for (int i = 0; i < 4; i++)
#pragma unroll
            for (int j = 0; j < 4; j++)
                acc[i][j] = mfma16(af[i], bfv[j], acc[i][j]);
    };

    const int nk = K >> 5;
    stage(0, 0);
    __syncthreads();
    int cur = 0;
    for (int kt = 0; kt < nk - 1; ++kt) {
        stage(cur ^ 1, (kt + 1) * 32);
        compute(cur);
        __syncthreads();
        cur ^= 1;
    }
    compute(cur);

#pragma unroll
    for (int j = 0; j < 4; j++) {
        const int gc = n0 + wc + j * 16 + lr;
        float bv = 0.f;
        if constexpr (EPI != 3) bv = bias[gc];
#pragma unroll
        for (int i = 0; i < 4; i++) {
            const int grb = m0 + wr + i * 16 + lg * 4;
#pragma unroll
            for (int r = 0; r < 4; r++) {
                float v = acc[i][j][r] + bv;
                if constexpr (EPI == 1) v = 0.5f * v * (1.f + erff(v * 0.70710678118654752f));
                const size_t o = (size_t)(grb + r) * N + gc;
                if constexpr (EPI == 3) outf[o] = v;
                else                    outb[o] = f2b(v);
            }
        }
    }
}

// ---------------------------------------------------------------------------
// 64x128 GEMM body (skinny-N occupancy), 4 waves of 64x32. EPI: 0 bias->bf16,
// 2 = bias + f32 resid +=
// ---------------------------------------------------------------------------
template <int EPI>
__device__ __forceinline__ void gemm64(
    const u16* __restrict__ A, const u16* __restrict__ Bt,
    const float* __restrict__ bias,
    float* __restrict__ outf, u16* __restrict__ outb,
    int M, int N, int K, int bm, int bn)
{
    __shared__ u16 lsA[2][64 * 32];
    __shared__ u16 lsB[2][128 * 32];
    const int tid  = threadIdx.x;
    const int w    = tid >> 6, lane = tid & 63;
    const int lr   = lane & 15, lg = lane >> 4;
    const int m0   = bm * 64, n0 = bn * 128;
    const int wc   = w * 32;
    f32x4 acc[4][2] = {};

    const int row0 = tid >> 2;
    const int ksw8 = ((lane & 3) ^ ((lane >> 3) & 3)) * 8;
    const u16* a0  = A  + (size_t)(m0 + row0) * K + ksw8;
    const u16* b0p = Bt + (size_t)(n0 + row0) * K + ksw8;
    const u16* b1p = b0p + (size_t)64 * K;
    const int rsw  = (lg ^ ((lr >> 1) & 3)) * 8;

    auto stage = [&](int buf, int ko) {
        char* la = (char*)lsA[buf] + w * 1024;
        char* lb = (char*)lsB[buf] + w * 1024;
        gload16(a0 + ko, la);
        gload16(b0p + ko, lb);
        gload16(b1p + ko, lb + 4096);
    };
    auto compute = [&](int buf) {
        bf16x8 af[4], bfv[2];
#pragma unroll
        for (int i = 0; i < 4; i++)
            af[i] = *(const bf16x8*)&lsA[buf][(i * 16 + lr) * 32 + rsw];
#pragma unroll
        for (int j = 0; j < 2; j++)
            bfv[j] = *(const bf16x8*)&lsB[buf][(wc + j * 16 + lr) * 32 + rsw];
#pragma unroll
        for (int i = 0; i < 4; i++)
#pragma unroll
            for (int j = 0; j < 2; j++)
                acc[i][j] = mfma16(af[i], bfv[j], acc[i][j]);
    };

    const int nk = K >> 5;
    stage(0, 0);
    __syncthreads();
    int cur = 0;
    for (int kt = 0; kt < nk - 1; ++kt) {
        stage(cur ^ 1, (kt + 1) * 32);
        compute(cur);
        __syncthreads();
        cur ^= 1;
    }
    compute(cur);

#pragma unroll
    for (int j = 0; j < 2; j++) {
        const int gc = n0 + wc + j * 16 + lr;
        const float bv = bias[gc];
#pragma unroll
        for (int i = 0; i < 4; i++) {
            const int grb = m0 + i * 16 + lg * 4;
#pragma unroll
            for (int r = 0; r < 4; r++) {
                float v = acc[i][j][r] + bv;
                const size_t o = (size_t)(grb + r) * N + gc;
                if constexpr (EPI == 2) outf[o] += v;
                else                    outb[o] = f2b(v);
            }
        }
    }
}

__global__ __launch_bounds__(256) void gemm64_bias_k(
    const u16* A, const u16* Bt, const float* bias, u16* out, int M, int N, int K, int nbm)
{
    int2 b = swz_bmbn(nbm);
    gemm64<0>(A, Bt, bias, nullptr, out, M, N, K, b.x, b.y);
}
__global__ __launch_bounds__(256) void gemm64_resid_k(
    const u16* A, const u16* Bt, const float* bias, float* out, int M, int N, int K, int nbm)
{
    int2 b = swz_bmbn(nbm);
    gemm64<2>(A, Bt, bias, out, nullptr, M, N, K, b.x, b.y);
}
__global__ __launch_bounds__(256) void gemm128_gelu_k(
    const u16* A, const u16* Bt, const float* bias, u16* out, int M, int N, int K, int nbm)
{
    int2 b = swz_bmbn(nbm);
    gemm128<1>(A, Bt, bias, nullptr, out, M, N, K, b.x, b.y);
}
__global__ __launch_bounds__(256) void gemm128_plain_k(
    const u16* A, const u16* Bt, float* out, int M, int N, int K, int nbm)
{
    int2 b = swz_bmbn(nbm);
    gemm128<3>(A, Bt, nullptr, out, nullptr, M, N, K, b.x, b.y);
}

// ---------------------------------------------------------------------------
// Flash attention. qkv bf16 [T,3072] (q at col 0, k at col 1024); vT bf16 [D,T];
// out bf16 [T,1024]. 1 wave = 16 q-rows of one head; KV tiles of 32.
// ---------------------------------------------------------------------------
__global__ __launch_bounds__(256) void flash_attn_k(
    const u16* __restrict__ qkv, const u16* __restrict__ vT, u16* __restrict__ out)
{
    constexpr int DS = 3072, T = 2048;
    __shared__ u16 pbuf[4][512];
    const int w = threadIdx.x >> 6, lane = threadIdx.x & 63;
    const int lr = lane & 15, lg = lane >> 4;
    const int h  = blockIdx.y;
    const int qt = (gridDim.x - 1 - blockIdx.x) * 4 + w;   // longest jobs first
    const int q0 = qt * 16;
    const int hoff = h * 64;

    const u16* q = qkv;
    const u16* k = qkv + 1024;
    const bf16x8 qf0 = *(const bf16x8*)(q + (size_t)(q0 + lr) * DS + hoff + lg * 8);
    const bf16x8 qf1 = *(const bf16x8*)(q + (size_t)(q0 + lr) * DS + hoff + 32 + lg * 8);

    f32x4 oa[4] = {};
    float m_r[4] = {-1e30f, -1e30f, -1e30f, -1e30f};
    float l_r[4] = {};
    u16* pb = pbuf[w];

    const int ntiles = q0 / 32 + 1;
    for (int t = 0; t < ntiles; ++t) {
        const int kv0 = t * 32;
        f32x4 s0 = {}, s1 = {};
        {
            const u16* kb = k + (size_t)(kv0 + lr) * DS + hoff + lg * 8;
            s0 = mfma16(qf0, *(const bf16x8*)kb, s0);
            s0 = mfma16(qf1, *(const bf16x8*)(kb + 32), s0);
            const u16* kb1 = kb + (size_t)16 * DS;
            s1 = mfma16(qf0, *(const bf16x8*)kb1, s1);
            s1 = mfma16(qf1, *(const bf16x8*)(kb1 + 32), s1);
        }
        const bool needmask = (kv0 + 31 > q0);
        float p0[4], p1[4], alpha[4];
#pragma unroll
        for (int r = 0; r < 4; r++) {
            float v0 = s0[r] * 0.125f, v1 = s1[r] * 0.125f;
            if (needmask) {
                const int rg = q0 + lg * 4 + r;
                if (kv0 + lr > rg)      v0 = -1e30f;
                if (kv0 + 16 + lr > rg) v1 = -1e30f;
            }
            float mx = fmaxf(v0, v1);
            mx = fmaxf(mx, __shfl_xor(mx, 1));
            mx = fmaxf(mx, __shfl_xor(mx, 2));
            mx = fmaxf(mx, __shfl_xor(mx, 4));
            mx = fmaxf(mx, __shfl_xor(mx, 8));
            const float mn = fmaxf(m_r[r], mx);
            alpha[r] = __expf(m_r[r] - mn);
            m_r[r] = mn;
            p0[r] = __expf(v0 - mn);
            p1[r] = __expf(v1 - mn);
            float ps = p0[r] + p1[r];
            ps += __shfl_xor(ps, 1);
            ps += __shfl_xor(ps, 2);
            ps += __shfl_xor(ps, 4);
            ps += __shfl_xor(ps, 8);
            l_r[r] = l_r[r] * alpha[r] + ps;
        }
#pragma unroll
        for (int r = 0; r < 4; r++) {
            pb[(lg * 4 + r) * 32 + lr]      = f2b(p0[r]);
            pb[(lg * 4 + r) * 32 + 16 + lr] = f2b(p1[r]);
        }
        const bf16x8 pa = *(const bf16x8*)&pb[lr * 32 + lg * 8];
#pragma unroll
        for (int n = 0; n < 4; n++) {
#pragma unroll
            for (int r = 0; r < 4; r++) oa[n][r] *= alpha[r];
        }
#pragma unroll
        for (int n = 0; n < 4; n++) {
            const bf16x8 vf = *(const bf16x8*)(vT + (size_t)(hoff + n * 16 + lr) * T + kv0 + lg * 8);
            oa[n] = mfma16(pa, vf, oa[n]);
        }
    }
#pragma unroll
    for (int n = 0; n < 4; n++)
#pragma unroll
        for (int r = 0; r < 4; r++)
            out[(size_t)(q0 + lg * 4 + r) * 1024 + hoff + n * 16 + lr] = f2b(oa[n][r] / l_r[r]);
}

// ---------------------------------------------------------------------------
// Transpose + convert: src [K][N] f32 -> dst [N][K] bf16, per-z strides.
// ---------------------------------------------------------------------------
__global__ __launch_bounds__(256) void transpose_cvt_k(
    const float* __restrict__ src, u16* __restrict__ dst, int K, int N,
    long long srcLS, long long dstLS)
{
    __shared__ float tile[32][33];
    src += (size_t)blockIdx.z * srcLS;
    dst += (size_t)blockIdx.z * dstLS;
    const int n0 = blockIdx.x * 32, k0 = blockIdx.y * 32;
    const int tx = threadIdx.x & 31, ty = threadIdx.x >> 5;
#pragma unroll
    for (int r = 0; r < 32; r += 8)
        tile[ty + r][tx] = src[(size_t)(k0 + ty + r) * N + n0 + tx];
    __syncthreads();
#pragma unroll
    for (int r = 0; r < 32; r += 8)
        dst[(size_t)(n0 + ty + r) * K + k0 + tx] = f2b(tile[tx][ty + r]);
}

// bf16 transpose: src [R][C] (row stride srcStride) -> dst [C][R]
__global__ __launch_bounds__(256) void transpose_u16_k(
    const u16* __restrict__ src, u16* __restrict__ dst, int R, int C, int srcStride)
{
    __shared__ u16 tile[32][33];
    const int c0 = blockIdx.x * 32, r0 = blockIdx.y * 32;
    const int tx = threadIdx.x & 31, ty = threadIdx.x >> 5;
#pragma unroll
    for (int r = 0; r < 32; r += 8)
        tile[ty + r][tx] = src[(size_t)(r0 + ty + r) * srcStride + c0 + tx];
    __syncthreads();
#pragma unroll
    for (int r = 0; r < 32; r += 8)
        dst[(size_t)(c0 + ty + r) * R + r0 + tx] = tile[tx][ty + r];
}

// concat per-layer q/k/v biases into [L][3072]
__global__ __launch_bounds__(256) void concat_bias_k(
    const float* __restrict__ bq, const float* __restrict__ bk,
    const float* __restrict__ bv, float* __restrict__ bcat)
{
    const int l = blockIdx.y;
    const int j = blockIdx.x * 256 + threadIdx.x;
    float v;
    if (j < 1024)      v = bq[l * 1024 + j];
    else if (j < 2048) v = bk[l * 1024 + j - 1024];
    else               v = bv[l * 1024 + j - 2048];
    bcat[l * 3072 + j] = v;
}

// ---------------------------------------------------------------------------
__global__ __launch_bounds__(256) void embed_pos_k(
    const int* __restrict__ idx, const float* __restrict__ emb, float* __restrict__ x)
{
    const int t = blockIdx.x, tid = threadIdx.x;
    const int tok = idx[t];
    float4 e = ((const float4*)(emb + (size_t)tok * 1024))[tid];
    const int d0 = tid * 4;
    const float c = -0.0089944730195080f;      // -ln(10000)/1024
    const float a0 = (float)t * expf((float)d0 * c);
    const float a1 = (float)t * expf((float)(d0 + 2) * c);
    e.x += sinf(a0); e.y += cosf(a0); e.z += sinf(a1); e.w += cosf(a1);
    ((float4*)(x + (size_t)t * 1024))[tid] = e;
}

__global__ __launch_bounds__(256) void layernorm_k(
    const float* __restrict__ x, const float* __restrict__ g,
    const float* __restrict__ b, u16* __restrict__ out)
{
    __shared__ float red[8];
    const int row = blockIdx.x, tid = threadIdx.x;
    const int w = tid >> 6, lane = tid & 63;
    const float4 v = ((const float4*)(x + (size_t)row * 1024))[tid];
    float s = v.x + v.y + v.z + v.w;
#pragma unroll
    for (int d = 1; d < 64; d <<= 1) s += __shfl_xor(s, d);
    if (lane == 0) red[w] = s;
    __syncthreads();
    const float mu = (red[0] + red[1] + red[2] + red[3]) * (1.f / 1024.f);
    const float d0 = v.x - mu, d1 = v.y - mu, d2 = v.z - mu, d3 = v.w - mu;
    float s2 = d0 * d0 + d1 * d1 + d2 * d2 + d3 * d3;
#pragma unroll
    for (int d = 1; d < 64; d <<= 1) s2 += __shfl_xor(s2, d);
    if (lane == 0) red[4 + w] = s2;
    __syncthreads();
    const float var = (red[4] + red[5] + red[6] + red[7]) * (1.f / 1024.f);
    const float rs = rsqrtf(var + 1e-5f);
    const float4 gv = ((const float4*)g)[tid];
    const float4 bv = ((const float4*)b)[tid];
    u32 p0 = (u32)f2b(d0 * rs * gv.x + bv.x) | ((u32)f2b(d1 * rs * gv.y + bv.y) << 16);
    u32 p1 = (u32)f2b(d2 * rs * gv.z + bv.z) | ((u32)f2b(d3 * rs * gv.w + bv.w) << 16);
    ((uint2*)(out + (size_t)row * 1024))[tid] = make_uint2(p0, p1);
}

// ---------------------------------------------------------------------------
extern "C" void kernel_launch(void* const* d_in, const int* in_sizes, int n_in,
                              void* d_out, int out_size, void* d_ws, size_t ws_size,
                              hipStream_t stream)
{
    const int*   idx   = (const int*)  d_in[0];
    const float* embed = (const float*)d_in[1];
    const float* Wq    = (const float*)d_in[2];
    const float* Wk    = (const float*)d_in[3];
    const float* Wv    = (const float*)d_in[4];
    const float* Wo    = (const float*)d_in[5];
    const float* bq    = (const float*)d_in[6];
    const float* bk    = (const float*)d_in[7];
    const float* bv    = (const float*)d_in[8];
    const float* bo    = (const float*)d_in[9];
    const float* ln1g  = (const float*)d_in[10];
    const float* ln1b  = (const float*)d_in[11];
    const float* ln2g  = (const float*)d_in[12];
    const float* ln2b  = (const float*)d_in[13];
    const float* w1    = (const float*)d_in[14];
    const float* b1    = (const float*)d_in[15];
    const float* w2    = (const float*)d_in[16];
    const float* b2    = (const float*)d_in[17];
    const float* lnfg  = (const float*)d_in[18];
    const float* lnfb  = (const float*)d_in[19];
    const float* headw = (const float*)d_in[20];

    char* ws = (char*)d_ws;
    auto alloc = [&](size_t bytes) {
        char* p = ws;
        ws += (bytes + 255) & ~(size_t)255;
        return p;
    };
    u16*   qkvT = (u16*)alloc((size_t)4 * 3072 * 1024 * 2);
    u16*   WoT  = (u16*)alloc((size_t)4 * 1024 * 1024 * 2);
    u16*   w1T  = (u16*)alloc((size_t)4 * 1024 * 4096 * 2);
    u16*   w2T  = (u16*)alloc((size_t)4 * 1024 * 4096 * 2);
    u16*   hT   = (u16*)alloc((size_t)32000 * 1024 * 2);
    float* bcat = (float*)alloc((size_t)4 * 3072 * 4);
    float* x    = (float*)alloc((size_t)2048 * 1024 * 4);
    u16*   hb   = (u16*)alloc((size_t)2048 * 1024 * 2);
    u16*   qkvb = (u16*)alloc((size_t)2048 * 3072 * 2);
    u16*   vTb  = (u16*)alloc((size_t)2048 * 1024 * 2);
    u16*   ab   = (u16*)alloc((size_t)2048 * 1024 * 2);
    u16*   ff   = (u16*)alloc((size_t)2048 * 4096 * 2);

    // Weight conversion + transpose (re-done every call; no caching allowed)
    transpose_cvt_k<<<dim3(32, 32, 4),  256, 0, stream>>>(Wq, qkvT,            1024, 1024, 1048576, 3145728);
    transpose_cvt_k<<<dim3(32, 32, 4),  256, 0, stream>>>(Wk, qkvT + 1048576,  1024, 1024, 1048576, 3145728);
    transpose_cvt_k<<<dim3(32, 32, 4),  256, 0, stream>>>(Wv, qkvT + 2097152,  1024, 1024, 1048576, 3145728);
    transpose_cvt_k<<<dim3(32, 32, 4),  256, 0, stream>>>(Wo, WoT,             1024, 1024, 1048576, 1048576);
    transpose_cvt_k<<<dim3(128, 32, 4), 256, 0, stream>>>(w1, w1T,             1024, 4096, 4194304, 4194304);
    transpose_cvt_k<<<dim3(32, 128, 4), 256, 0, stream>>>(w2, w2T,             4096, 1024, 4194304, 4194304);
    transpose_cvt_k<<<dim3(1000, 32, 1), 256, 0, stream>>>(headw, hT,          1024, 32000, 0, 0);
    concat_bias_k<<<dim3(12, 4), 256, 0, stream>>>(bq, bk, bv, bcat);

    embed_pos_k<<<dim3(2048), 256, 0, stream>>>(idx, embed, x);

    for (int l = 0; l < 4; ++l) {
        layernorm_k<<<dim3(2048), 256, 0, stream>>>(x, ln1g + l * 1024, ln1b + l * 1024, hb);
        gemm64_bias_k<<<dim3(768), 256, 0, stream>>>(hb, qkvT + (size_t)l * 3145728,
                                                     bcat + l * 3072, qkvb, 2048, 3072, 1024, 32);
        transpose_u16_k<<<dim3(32, 64), 256, 0, stream>>>(qkvb + 2048, vTb, 2048, 1024, 3072);
        flash_attn_k<<<dim3(32, 16), 256, 0, stream>>>(qkvb, vTb, ab);
        gemm64_resid_k<<<dim3(256), 256, 0, stream>>>(ab, WoT + (size_t)l * 1048576,
                                                      bo + l * 1024, x, 2048, 1024, 1024, 32);
        layernorm_k<<<dim3(2048), 256, 0, stream>>>(x, ln2g + l * 1024, ln2b + l * 1024, hb);
        gemm128_gelu_k<<<dim3(512), 256, 0, stream>>>(hb, w1T + (size_t)l * 4194304,
                                                      b1 + l * 4096, ff, 2048, 4096, 1024, 16);
        gemm64_resid_k<<<dim3(256), 256, 0, stream>>>(ff, w2T + (size_t)l * 4194304,
                                                      b2 + l * 1024, x, 2048, 1024, 4096, 32);
    }
    layernorm_k<<<dim3(2048), 256, 0, stream>>>(x, lnfg, lnfb, hb);
    gemm128_plain_k<<<dim3(4000), 256, 0, stream>>>(hb, hT, (float*)d_out, 2048, 32000, 1024, 16);
}

// Round 3
// 1245.218 us; speedup vs baseline: 1.3882x; 1.2139x over previous
//
#include <hip/hip_runtime.h>
#include <cstdint>

using u16 = unsigned short;
using u32 = unsigned int;
typedef __bf16  bf16x8 __attribute__((ext_vector_type(8)));
typedef float   f32x4  __attribute__((ext_vector_type(4)));
typedef float   f32x16 __attribute__((ext_vector_type(16)));

__device__ __forceinline__ u16 f2b(float x) {
    u32 u = __builtin_bit_cast(u32, x);
    u = (u + 0x7fffu + ((u >> 16) & 1u)) >> 16;
    return (u16)u;
}

__device__ __forceinline__ f32x4 mfma16(bf16x8 a, bf16x8 b, f32x4 c) {
    return __builtin_amdgcn_mfma_f32_16x16x32_bf16(a, b, c, 0, 0, 0);
}
__device__ __forceinline__ f32x16 mfma32(bf16x8 a, bf16x8 b, f32x16 c) {
    return __builtin_amdgcn_mfma_f32_32x32x16_bf16(a, b, c, 0, 0, 0);
}

__device__ __forceinline__ void gload16(const void* g, void* lds) {
    auto gp = (__attribute__((address_space(1))) void*)(uintptr_t)g;
    auto lp = (__attribute__((address_space(3))) void*)(uintptr_t)lds;
    __builtin_amdgcn_global_load_lds(gp, lp, 16, 0, 0);
}

// bijective XCD-aware swizzle (m204); bm fastest so co-resident blocks share B panels
__device__ __forceinline__ int2 swz_bmbn(int nbm) {
    const int nwg = gridDim.x, orig = blockIdx.x;
    const int q = nwg >> 3, r = nwg & 7;
    const int xcd = orig & 7, lin = orig >> 3;
    const int id = (xcd < r ? xcd * (q + 1) : r * (q + 1) + (xcd - r) * q) + lin;
    return make_int2(id % nbm, id / nbm);
}

// ---------------------------------------------------------------------------
// 128x128 GEMM body, BK=32, dbuf LDS, k-slot XOR swizzle (2-way conflicts).
// EPI: 1 = bias+gelu->bf16, 3 = plain f32
// ---------------------------------------------------------------------------
template <int EPI>
__device__ __forceinline__ void gemm128(
    const u16* __restrict__ A, const u16* __restrict__ Bt,
    const float* __restrict__ bias,
    float* __restrict__ outf, u16* __restrict__ outb,
    int M, int N, int K, int bm, int bn)
{
    __shared__ u16 lsA[2][128 * 32];
    __shared__ u16 lsB[2][128 * 32];
    const int tid  = threadIdx.x;
    const int w    = tid >> 6, lane = tid & 63;
    const int lr   = lane & 15, lg = lane >> 4;
    const int m0   = bm * 128, n0 = bn * 128;
    const int wr   = (w >> 1) * 64, wc = (w & 1) * 64;
    f32x4 acc[4][4] = {};

    const int row0 = tid >> 2;
    const int ksw8 = ((lane & 3) ^ ((lane >> 3) & 3)) * 8;
    const u16* a0  = A  + (size_t)(m0 + row0) * K + ksw8;
    const u16* a1  = a0 + (size_t)64 * K;
    const u16* b0p = Bt + (size_t)(n0 + row0) * K + ksw8;
    const u16* b1p = b0p + (size_t)64 * K;
    const int rsw  = (lg ^ ((lr >> 1) & 3)) * 8;

    auto stage = [&](int buf, int ko) {
        char* la = (char*)lsA[buf] + w * 1024;
        char* lb = (char*)lsB[buf] + w * 1024;
        gload16(a0 + ko, la);
        gload16(a1 + ko, la + 4096);
        gload16(b0p + ko, lb);
        gload16(b1p + ko, lb + 4096);
    };
    auto compute = [&](int buf) {
        bf16x8 af[4], bfv[4];
#pragma unroll
        for (int i = 0; i < 4; i++)
            af[i] = *(const bf16x8*)&lsA[buf][(wr + i * 16 + lr) * 32 + rsw];
#pragma unroll
        for (int j = 0; j < 4; j++)
            bfv[j] = *(const bf16x8*)&lsB[buf][(wc + j * 16 + lr) * 32 + rsw];
#pragma unroll
        for (int i = 0; i < 4; i++)
#pragma unroll
            for (int j = 0; j < 4; j++)
                acc[i][j] = mfma16(af[i], bfv[j], acc[i][j]);
    };

    const int nk = K >> 5;
    stage(0, 0);
    __syncthreads();
    int cur = 0;
    for (int kt = 0; kt < nk - 1; ++kt) {
        stage(cur ^ 1, (kt + 1) * 32);
        compute(cur);
        __syncthreads();
        cur ^= 1;
    }
    compute(cur);

#pragma unroll
    for (int j = 0; j < 4; j++) {
        const int gc = n0 + wc + j * 16 + lr;
        float bv = 0.f;
        if constexpr (EPI != 3) bv = bias[gc];
#pragma unroll
        for (int i = 0; i < 4; i++) {
            const int grb = m0 + wr + i * 16 + lg * 4;
#pragma unroll
            for (int r = 0; r < 4; r++) {
                float v = acc[i][j][r] + bv;
                if constexpr (EPI == 1) v = 0.5f * v * (1.f + erff(v * 0.70710678118654752f));
                const size_t o = (size_t)(grb + r) * N + gc;
                if constexpr (EPI == 3) outf[o] = v;
                else                    outb[o] = f2b(v);
            }
        }
    }
}

// ---------------------------------------------------------------------------
// 64x128 GEMM body (skinny-N occupancy), 4 waves of 64x32. EPI: 0 bias->bf16,
// 2 = bias + f32 resid +=
// ---------------------------------------------------------------------------
template <int EPI>
__device__ __forceinline__ void gemm64(
    const u16* __restrict__ A, const u16* __restrict__ Bt,
    const float* __restrict__ bias,
    float* __restrict__ outf, u16* __restrict__ outb,
    int M, int N, int K, int bm, int bn)
{
    __shared__ u16 lsA[2][64 * 32];
    __shared__ u16 lsB[2][128 * 32];
    const int tid  = threadIdx.x;
    const int w    = tid >> 6, lane = tid & 63;
    const int lr   = lane & 15, lg = lane >> 4;
    const int m0   = bm * 64, n0 = bn * 128;
    const int wc   = w * 32;
    f32x4 acc[4][2] = {};

    const int row0 = tid >> 2;
    const int ksw8 = ((lane & 3) ^ ((lane >> 3) & 3)) * 8;
    const u16* a0  = A  + (size_t)(m0 + row0) * K + ksw8;
    const u16* b0p = Bt + (size_t)(n0 + row0) * K + ksw8;
    const u16* b1p = b0p + (size_t)64 * K;
    const int rsw  = (lg ^ ((lr >> 1) & 3)) * 8;

    auto stage = [&](int buf, int ko) {
        char* la = (char*)lsA[buf] + w * 1024;
        char* lb = (char*)lsB[buf] + w * 1024;
        gload16(a0 + ko, la);
        gload16(b0p + ko, lb);
        gload16(b1p + ko, lb + 4096);
    };
    auto compute = [&](int buf) {
        bf16x8 af[4], bfv[2];
#pragma unroll
        for (int i = 0; i < 4; i++)
            af[i] = *(const bf16x8*)&lsA[buf][(i * 16 + lr) * 32 + rsw];
#pragma unroll
        for (int j = 0; j < 2; j++)
            bfv[j] = *(const bf16x8*)&lsB[buf][(wc + j * 16 + lr) * 32 + rsw];
#pragma unroll
        for (int i = 0; i < 4; i++)
#pragma unroll
            for (int j = 0; j < 2; j++)
                acc[i][j] = mfma16(af[i], bfv[j], acc[i][j]);
    };

    const int nk = K >> 5;
    stage(0, 0);
    __syncthreads();
    int cur = 0;
    for (int kt = 0; kt < nk - 1; ++kt) {
        stage(cur ^ 1, (kt + 1) * 32);
        compute(cur);
        __syncthreads();
        cur ^= 1;
    }
    compute(cur);

#pragma unroll
    for (int j = 0; j < 2; j++) {
        const int gc = n0 + wc + j * 16 + lr;
        const float bv = bias[gc];
#pragma unroll
        for (int i = 0; i < 4; i++) {
            const int grb = m0 + i * 16 + lg * 4;
#pragma unroll
            for (int r = 0; r < 4; r++) {
                float v = acc[i][j][r] + bv;
                const size_t o = (size_t)(grb + r) * N + gc;
                if constexpr (EPI == 2) outf[o] += v;
                else                    outb[o] = f2b(v);
            }
        }
    }
}

__global__ __launch_bounds__(256) void gemm64_bias_k(
    const u16* A, const u16* Bt, const float* bias, u16* out, int M, int N, int K, int nbm)
{
    int2 b = swz_bmbn(nbm);
    gemm64<0>(A, Bt, bias, nullptr, out, M, N, K, b.x, b.y);
}
__global__ __launch_bounds__(256) void gemm64_resid_k(
    const u16* A, const u16* Bt, const float* bias, float* out, int M, int N, int K, int nbm)
{
    int2 b = swz_bmbn(nbm);
    gemm64<2>(A, Bt, bias, out, nullptr, M, N, K, b.x, b.y);
}
__global__ __launch_bounds__(256) void gemm128_gelu_k(
    const u16* A, const u16* Bt, const float* bias, u16* out, int M, int N, int K, int nbm)
{
    int2 b = swz_bmbn(nbm);
    gemm128<1>(A, Bt, bias, nullptr, out, M, N, K, b.x, b.y);
}
__global__ __launch_bounds__(256) void gemm128_plain_k(
    const u16* A, const u16* Bt, float* out, int M, int N, int K, int nbm)
{
    int2 b = swz_bmbn(nbm);
    gemm128<3>(A, Bt, nullptr, out, nullptr, M, N, K, b.x, b.y);
}

// ---------------------------------------------------------------------------
// Flash attention, swapped-operand 32x32x16 structure (m214 port).
// qkv bf16 [T,3072] (q col 0, k col 1024); vT bf16 [1024,T]; out bf16 [T,1024].
// 1 wave = 32 q-rows; each q-tile split across a parity PAIR of waves
// (even/odd 64-wide KV tiles) merged at the end (flash merge).
// S^T = mfma(K,Q): lane owns q-col = lane&31 -> softmax is in-register.
// PV computes O^T = mfma(V^T, P^T): rescale is lane-local.
// Block: 4 waves = 2 q-tiles (qt, 63-qt) -> constant work per block.
// ---------------------------------------------------------------------------
__global__ __launch_bounds__(256) void flash_attn_k(
    const u16* __restrict__ qkv, const u16* __restrict__ vT, u16* __restrict__ out)
{
    constexpr int DS = 3072, T = 2048;
    __shared__ float mrg[2][64][32];          // [pair][d][q] 16 KB, conflict-free
    __shared__ float msh[2][32], lsh[2][32];
    __shared__ u16   sbuf[2][32 * 68];        // padded transpose buf (136B rows)
    const int w = threadIdx.x >> 6, lane = threadIdx.x & 63;
    const int lq = lane & 31, hi = lane >> 5;
    const int hoff = blockIdx.y * 64;
    const int pair = w >> 1, par = w & 1;
    const int qt = (pair == 0) ? blockIdx.x : 63 - blockIdx.x;
    const int q0 = qt * 32;
    const int qg = q0 + lq;

    const u16* qp = qkv + (size_t)qg * DS + hoff;
    const u16* kp = qkv + 1024 + hoff;

    bf16x8 qf[4];
#pragma unroll
    for (int d = 0; d < 4; d++)
        qf[d] = *(const bf16x8*)(qp + d * 16 + hi * 8);

    f32x16 o0 = {}, o1 = {};
    float m_r = -1e30f, l_r = 0.f;

    const int ntiles = (qt >> 1) + 1;
    for (int t = par; t < ntiles; t += 2) {
        const int kv0 = t * 64;
        // ---- QK^T (swapped): S^T[kv][q], two 32-kv subtiles ----
        f32x16 s0 = {}, s1 = {};
        {
            const u16* kb0 = kp + (size_t)(kv0 + lq) * DS + hi * 8;
            const u16* kb1 = kb0 + (size_t)32 * DS;
#pragma unroll
            for (int d = 0; d < 4; d++) {
                s0 = mfma32(*(const bf16x8*)(kb0 + d * 16), qf[d], s0);
                s1 = mfma32(*(const bf16x8*)(kb1 + d * 16), qf[d], s1);
            }
        }
        // ---- mask + scale + per-lane stats ----
        float p[32];
        float mx = -1e30f;
#pragma unroll
        for (int r = 0; r < 16; r++) {
            const int kvl = (r & 3) + 8 * (r >> 2) + 4 * hi;
            float v0 = (kv0 + kvl      <= qg) ? s0[r] * 0.125f : -1e30f;
            float v1 = (kv0 + 32 + kvl <= qg) ? s1[r] * 0.125f : -1e30f;
            p[r] = v0; p[16 + r] = v1;
            mx = fmaxf(mx, fmaxf(v0, v1));
        }
        mx = fmaxf(mx, __shfl_xor(mx, 32));
        const float mn = fmaxf(m_r, mx);
        const float alpha = __expf(m_r - mn);
        m_r = mn;
        float ls = 0.f;
#pragma unroll
        for (int i = 0; i < 32; i++) { p[i] = __expf(p[i] - mn); ls += p[i]; }
        ls += __shfl_xor(ls, 32);
        l_r = l_r * alpha + ls;
#pragma unroll
        for (int r = 0; r < 16; r++) { o0[r] *= alpha; o1[r] *= alpha; }
        // ---- P -> bf16 fragments (T12 pattern) + PV per subtile ----
#pragma unroll
        for (int sub = 0; sub < 2; sub++) {
            u32 pw[8], x[8];
#pragma unroll
            for (int i = 0; i < 8; i++)
                pw[i] = (u32)f2b(p[sub * 16 + 2 * i]) | ((u32)f2b(p[sub * 16 + 2 * i + 1]) << 16);
#pragma unroll
            for (int i = 0; i < 8; i++) x[i] = __shfl_xor(pw[i], 32);
            u32 b0[4], b1[4];
            b0[0] = hi ? x[2]  : pw[0];  b0[1] = hi ? x[3]  : pw[1];
            b0[2] = hi ? pw[2] : x[0];   b0[3] = hi ? pw[3] : x[1];
            b1[0] = hi ? x[6]  : pw[4];  b1[1] = hi ? x[7]  : pw[5];
            b1[2] = hi ? pw[6] : x[4];   b1[3] = hi ? pw[7] : x[5];
            bf16x8 B0 = __builtin_bit_cast(bf16x8, *(const uint4*)b0);
            bf16x8 B1 = __builtin_bit_cast(bf16x8, *(const uint4*)b1);
            const u16* vb = vT + (size_t)(hoff + lq) * T + kv0 + sub * 32 + hi * 8;
            o0 = mfma32(*(const bf16x8*)vb, B0, o0);
            o0 = mfma32(*(const bf16x8*)(vb + 16), B1, o0);
            const u16* vb1 = vb + (size_t)32 * T;
            o1 = mfma32(*(const bf16x8*)vb1, B0, o1);
            o1 = mfma32(*(const bf16x8*)(vb1 + 16), B1, o1);
        }
    }

    // ---- flash merge of parity pair + transposed store ----
    __syncthreads();
    if (par == 0) {
#pragma unroll
        for (int r = 0; r < 16; r++) {
            const int d = (r & 3) + 8 * (r >> 2) + 4 * hi;
            mrg[pair][d][lq]      = o0[r];
            mrg[pair][d + 32][lq] = o1[r];
        }
        if (hi == 0) { msh[pair][lq] = m_r; lsh[pair][lq] = l_r; }
    }
    __syncthreads();
    if (par == 1) {
        const float m0v = msh[pair][lq], l0v = lsh[pair][lq];
        const float M = fmaxf(m0v, m_r);
        const float f0 = __expf(m0v - M), f1 = __expf(m_r - M);
        const float linv = 1.f / (l0v * f0 + l_r * f1);
        u32* sb = (u32*)sbuf[pair];
#pragma unroll
        for (int r = 0; r < 16; r += 2) {
            const int d = (r & 3) + 8 * (r >> 2) + 4 * hi;
            float va = (mrg[pair][d][lq] * f0 + o0[r] * f1) * linv;
            float vb = (mrg[pair][d + 1][lq] * f0 + o0[r + 1] * f1) * linv;
            sb[lq * 34 + (d >> 1)] = (u32)f2b(va) | ((u32)f2b(vb) << 16);
            float vc = (mrg[pair][d + 32][lq] * f0 + o1[r] * f1) * linv;
            float vd = (mrg[pair][d + 33][lq] * f0 + o1[r + 1] * f1) * linv;
            sb[lq * 34 + ((d + 32) >> 1)] = (u32)f2b(vc) | ((u32)f2b(vd) << 16);
        }
        // coalesced store: 8 passes x 4 rows, 16 lanes x 8B per row
#pragma unroll
        for (int ps = 0; ps < 8; ps++) {
            const int row = ps * 4 + (lane >> 4);
            const uint2 v = *(const uint2*)&sbuf[pair][row * 68 + (lane & 15) * 4];
            *(uint2*)(out + (size_t)(q0 + row) * 1024 + hoff + (lane & 15) * 4) = v;
        }
    }
}

// ---------------------------------------------------------------------------
// Transpose + convert: src [K][N] f32 -> dst [N][K] bf16, per-z strides.
// ---------------------------------------------------------------------------
__global__ __launch_bounds__(256) void transpose_cvt_k(
    const float* __restrict__ src, u16* __restrict__ dst, int K, int N,
    long long srcLS, long long dstLS)
{
    __shared__ float tile[32][33];
    src += (size_t)blockIdx.z * srcLS;
    dst += (size_t)blockIdx.z * dstLS;
    const int n0 = blockIdx.x * 32, k0 = blockIdx.y * 32;
    const int tx = threadIdx.x & 31, ty = threadIdx.x >> 5;
#pragma unroll
    for (int r = 0; r < 32; r += 8)
        tile[ty + r][tx] = src[(size_t)(k0 + ty + r) * N + n0 + tx];
    __syncthreads();
#pragma unroll
    for (int r = 0; r < 32; r += 8)
        dst[(size_t)(n0 + ty + r) * K + k0 + tx] = f2b(tile[tx][ty + r]);
}

// bf16 transpose: src [R][C] (row stride srcStride) -> dst [C][R]
__global__ __launch_bounds__(256) void transpose_u16_k(
    const u16* __restrict__ src, u16* __restrict__ dst, int R, int C, int srcStride)
{
    __shared__ u16 tile[32][33];
    const int c0 = blockIdx.x * 32, r0 = blockIdx.y * 32;
    const int tx = threadIdx.x & 31, ty = threadIdx.x >> 5;
#pragma unroll
    for (int r = 0; r < 32; r += 8)
        tile[ty + r][tx] = src[(size_t)(r0 + ty + r) * srcStride + c0 + tx];
    __syncthreads();
#pragma unroll
    for (int r = 0; r < 32; r += 8)
        dst[(size_t)(c0 + ty + r) * R + r0 + tx] = tile[tx][ty + r];
}

// concat per-layer q/k/v biases into [L][3072]
__global__ __launch_bounds__(256) void concat_bias_k(
    const float* __restrict__ bq, const float* __restrict__ bk,
    const float* __restrict__ bv, float* __restrict__ bcat)
{
    const int l = blockIdx.y;
    const int j = blockIdx.x * 256 + threadIdx.x;
    float v;
    if (j < 1024)      v = bq[l * 1024 + j];
    else if (j < 2048) v = bk[l * 1024 + j - 1024];
    else               v = bv[l * 1024 + j - 2048];
    bcat[l * 3072 + j] = v;
}

// ---------------------------------------------------------------------------
__global__ __launch_bounds__(256) void embed_pos_k(
    const int* __restrict__ idx, const float* __restrict__ emb, float* __restrict__ x)
{
    const int t = blockIdx.x, tid = threadIdx.x;
    const int tok = idx[t];
    float4 e = ((const float4*)(emb + (size_t)tok * 1024))[tid];
    const int d0 = tid * 4;
    const float c = -0.0089944730195080f;      // -ln(10000)/1024
    const float a0 = (float)t * expf((float)d0 * c);
    const float a1 = (float)t * expf((float)(d0 + 2) * c);
    e.x += sinf(a0); e.y += cosf(a0); e.z += sinf(a1); e.w += cosf(a1);
    ((float4*)(x + (size_t)t * 1024))[tid] = e;
}

__global__ __launch_bounds__(256) void layernorm_k(
    const float* __restrict__ x, const float* __restrict__ g,
    const float* __restrict__ b, u16* __restrict__ out)
{
    __shared__ float red[8];
    const int row = blockIdx.x, tid = threadIdx.x;
    const int w = tid >> 6, lane = tid & 63;
    const float4 v = ((const float4*)(x + (size_t)row * 1024))[tid];
    float s = v.x + v.y + v.z + v.w;
#pragma unroll
    for (int d = 1; d < 64; d <<= 1) s += __shfl_xor(s, d);
    if (lane == 0) red[w] = s;
    __syncthreads();
    const float mu = (red[0] + red[1] + red[2] + red[3]) * (1.f / 1024.f);
    const float d0 = v.x - mu, d1 = v.y - mu, d2 = v.z - mu, d3 = v.w - mu;
    float s2 = d0 * d0 + d1 * d1 + d2 * d2 + d3 * d3;
#pragma unroll
    for (int d = 1; d < 64; d <<= 1) s2 += __shfl_xor(s2, d);
    if (lane == 0) red[4 + w] = s2;
    __syncthreads();
    const float var = (red[4] + red[5] + red[6] + red[7]) * (1.f / 1024.f);
    const float rs = rsqrtf(var + 1e-5f);
    const float4 gv = ((const float4*)g)[tid];
    const float4 bv = ((const float4*)b)[tid];
    u32 p0 = (u32)f2b(d0 * rs * gv.x + bv.x) | ((u32)f2b(d1 * rs * gv.y + bv.y) << 16);
    u32 p1 = (u32)f2b(d2 * rs * gv.z + bv.z) | ((u32)f2b(d3 * rs * gv.w + bv.w) << 16);
    ((uint2*)(out + (size_t)row * 1024))[tid] = make_uint2(p0, p1);
}

// ---------------------------------------------------------------------------
extern "C" void kernel_launch(void* const* d_in, const int* in_sizes, int n_in,
                              void* d_out, int out_size, void* d_ws, size_t ws_size,
                              hipStream_t stream)
{
    const int*   idx   = (const int*)  d_in[0];
    const float* embed = (const float*)d_in[1];
    const float* Wq    = (const float*)d_in[2];
    const float* Wk    = (const float*)d_in[3];
    const float* Wv    = (const float*)d_in[4];
    const float* Wo    = (const float*)d_in[5];
    const float* bq    = (const float*)d_in[6];
    const float* bk    = (const float*)d_in[7];
    const float* bv    = (const float*)d_in[8];
    const float* bo    = (const float*)d_in[9];
    const float* ln1g  = (const float*)d_in[10];
    const float* ln1b  = (const float*)d_in[11];
    const float* ln2g  = (const float*)d_in[12];
    const float* ln2b  = (const float*)d_in[13];
    const float* w1    = (const float*)d_in[14];
    const float* b1    = (const float*)d_in[15];
    const float* w2    = (const float*)d_in[16];
    const float* b2    = (const float*)d_in[17];
    const float* lnfg  = (const float*)d_in[18];
    const float* lnfb  = (const float*)d_in[19];
    const float* headw = (const float*)d_in[20];

    char* ws = (char*)d_ws;
    auto alloc = [&](size_t bytes) {
        char* p = ws;
        ws += (bytes + 255) & ~(size_t)255;
        return p;
    };
    u16*   qkvT = (u16*)alloc((size_t)4 * 3072 * 1024 * 2);
    u16*   WoT  = (u16*)alloc((size_t)4 * 1024 * 1024 * 2);
    u16*   w1T  = (u16*)alloc((size_t)4 * 1024 * 4096 * 2);
    u16*   w2T  = (u16*)alloc((size_t)4 * 1024 * 4096 * 2);
    u16*   hT   = (u16*)alloc((size_t)32000 * 1024 * 2);
    float* bcat = (float*)alloc((size_t)4 * 3072 * 4);
    float* x    = (float*)alloc((size_t)2048 * 1024 * 4);
    u16*   hb   = (u16*)alloc((size_t)2048 * 1024 * 2);
    u16*   qkvb = (u16*)alloc((size_t)2048 * 3072 * 2);
    u16*   vTb  = (u16*)alloc((size_t)2048 * 1024 * 2);
    u16*   ab   = (u16*)alloc((size_t)2048 * 1024 * 2);
    u16*   ff   = (u16*)alloc((size_t)2048 * 4096 * 2);

    // Weight conversion + transpose (re-done every call; no caching allowed)
    transpose_cvt_k<<<dim3(32, 32, 4),  256, 0, stream>>>(Wq, qkvT,            1024, 1024, 1048576, 3145728);
    transpose_cvt_k<<<dim3(32, 32, 4),  256, 0, stream>>>(Wk, qkvT + 1048576,  1024, 1024, 1048576, 3145728);
    transpose_cvt_k<<<dim3(32, 32, 4),  256, 0, stream>>>(Wv, qkvT + 2097152,  1024, 1024, 1048576, 3145728);
    transpose_cvt_k<<<dim3(32, 32, 4),  256, 0, stream>>>(Wo, WoT,             1024, 1024, 1048576, 1048576);
    transpose_cvt_k<<<dim3(128, 32, 4), 256, 0, stream>>>(w1, w1T,             1024, 4096, 4194304, 4194304);
    transpose_cvt_k<<<dim3(32, 128, 4), 256, 0, stream>>>(w2, w2T,             4096, 1024, 4194304, 4194304);
    transpose_cvt_k<<<dim3(1000, 32, 1), 256, 0, stream>>>(headw, hT,          1024, 32000, 0, 0);
    concat_bias_k<<<dim3(12, 4), 256, 0, stream>>>(bq, bk, bv, bcat);

    embed_pos_k<<<dim3(2048), 256, 0, stream>>>(idx, embed, x);

    for (int l = 0; l < 4; ++l) {
        layernorm_k<<<dim3(2048), 256, 0, stream>>>(x, ln1g + l * 1024, ln1b + l * 1024, hb);
        gemm64_bias_k<<<dim3(768), 256, 0, stream>>>(hb, qkvT + (size_t)l * 3145728,
                                                     bcat + l * 3072, qkvb, 2048, 3072, 1024, 32);
        transpose_u16_k<<<dim3(32, 64), 256, 0, stream>>>(qkvb + 2048, vTb, 2048, 1024, 3072);
        flash_attn_k<<<dim3(32, 16), 256, 0, stream>>>(qkvb, vTb, ab);
        gemm64_resid_k<<<dim3(256), 256, 0, stream>>>(ab, WoT + (size_t)l * 1048576,
                                                      bo + l * 1024, x, 2048, 1024, 1024, 32);
        layernorm_k<<<dim3(2048), 256, 0, stream>>>(x, ln2g + l * 1024, ln2b + l * 1024, hb);
        gemm128_gelu_k<<<dim3(512), 256, 0, stream>>>(hb, w1T + (size_t)l * 4194304,
                                                      b1 + l * 4096, ff, 2048, 4096, 1024, 16);
        gemm64_resid_k<<<dim3(256), 256, 0, stream>>>(ff, w2T + (size_t)l * 4194304,
                                                      b2 + l * 1024, x, 2048, 1024, 4096, 32);
    }
    layernorm_k<<<dim3(2048), 256, 0, stream>>>(x, lnfg, lnfb, hb);
    gemm128_plain_k<<<dim3(4000), 256, 0, stream>>>(hb, hT, (float*)d_out, 2048, 32000, 1024, 16);
}

// Round 4
// 1088.707 us; speedup vs baseline: 1.5878x; 1.1438x over previous
//
#include <hip/hip_runtime.h>
#include <cstdint>

using u16 = unsigned short;
using u32 = unsigned int;
typedef __bf16  bf16x8 __attribute__((ext_vector_type(8)));
typedef float   f32x4  __attribute__((ext_vector_type(4)));
typedef float   f32x16 __attribute__((ext_vector_type(16)));

__device__ __forceinline__ u16 f2b(float x) {
    u32 u = __builtin_bit_cast(u32, x);
    u = (u + 0x7fffu + ((u >> 16) & 1u)) >> 16;
    return (u16)u;
}

__device__ __forceinline__ f32x4 mfma16(bf16x8 a, bf16x8 b, f32x4 c) {
    return __builtin_amdgcn_mfma_f32_16x16x32_bf16(a, b, c, 0, 0, 0);
}
__device__ __forceinline__ f32x16 mfma32(bf16x8 a, bf16x8 b, f32x16 c) {
    return __builtin_amdgcn_mfma_f32_32x32x16_bf16(a, b, c, 0, 0, 0);
}

__device__ __forceinline__ void gload16(const void* g, void* lds) {
    auto gp = (__attribute__((address_space(1))) void*)(uintptr_t)g;
    auto lp = (__attribute__((address_space(3))) void*)(uintptr_t)lds;
    __builtin_amdgcn_global_load_lds(gp, lp, 16, 0, 0);
}

// bijective XCD-aware swizzle (m204); bm fastest so co-resident blocks share B panels
__device__ __forceinline__ int2 swz_bmbn(int nbm) {
    const int nwg = gridDim.x, orig = blockIdx.x;
    const int q = nwg >> 3, r = nwg & 7;
    const int xcd = orig & 7, lin = orig >> 3;
    const int id = (xcd < r ? xcd * (q + 1) : r * (q + 1) + (xcd - r) * q) + lin;
    return make_int2(id % nbm, id / nbm);
}

// ---------------------------------------------------------------------------
// 128x128 GEMM body, BK=32, dbuf LDS, k-slot XOR swizzle (2-way conflicts).
// EPI: 1 = bias+gelu->bf16, 3 = plain f32
// ---------------------------------------------------------------------------
template <int EPI>
__device__ __forceinline__ void gemm128(
    const u16* __restrict__ A, const u16* __restrict__ Bt,
    const float* __restrict__ bias,
    float* __restrict__ outf, u16* __restrict__ outb,
    int M, int N, int K, int bm, int bn)
{
    __shared__ u16 lsA[2][128 * 32];
    __shared__ u16 lsB[2][128 * 32];
    const int tid  = threadIdx.x;
    const int w    = tid >> 6, lane = tid & 63;
    const int lr   = lane & 15, lg = lane >> 4;
    const int m0   = bm * 128, n0 = bn * 128;
    const int wr   = (w >> 1) * 64, wc = (w & 1) * 64;
    f32x4 acc[4][4] = {};

    const int row0 = tid >> 2;
    const int ksw8 = ((lane & 3) ^ ((lane >> 3) & 3)) * 8;
    const u16* a0  = A  + (size_t)(m0 + row0) * K + ksw8;
    const u16* a1  = a0 + (size_t)64 * K;
    const u16* b0p = Bt + (size_t)(n0 + row0) * K + ksw8;
    const u16* b1p = b0p + (size_t)64 * K;
    const int rsw  = (lg ^ ((lr >> 1) & 3)) * 8;

    auto stage = [&](int buf, int ko) {
        char* la = (char*)lsA[buf] + w * 1024;
        char* lb = (char*)lsB[buf] + w * 1024;
        gload16(a0 + ko, la);
        gload16(a1 + ko, la + 4096);
        gload16(b0p + ko, lb);
        gload16(b1p + ko, lb + 4096);
    };
    auto compute = [&](int buf) {
        bf16x8 af[4], bfv[4];
#pragma unroll
        for (int i = 0; i < 4; i++)
            af[i] = *(const bf16x8*)&lsA[buf][(wr + i * 16 + lr) * 32 + rsw];
#pragma unroll
        for (int j = 0; j < 4; j++)
            bfv[j] = *(const bf16x8*)&lsB[buf][(wc + j * 16 + lr) * 32 + rsw];
#pragma unroll
        for (int i = 0; i < 4; i++)
#pragma unroll
            for (int j = 0; j < 4; j++)
                acc[i][j] = mfma16(af[i], bfv[j], acc[i][j]);
    };

    const int nk = K >> 5;
    stage(0, 0);
    __syncthreads();
    int cur = 0;
    for (int kt = 0; kt < nk - 1; ++kt) {
        stage(cur ^ 1, (kt + 1) * 32);
        compute(cur);
        __syncthreads();
        cur ^= 1;
    }
    compute(cur);

#pragma unroll
    for (int j = 0; j < 4; j++) {
        const int gc = n0 + wc + j * 16 + lr;
        float bv = 0.f;
        if constexpr (EPI == 1) bv = bias[gc];
#pragma unroll
        for (int i = 0; i < 4; i++) {
            const int grb = m0 + wr + i * 16 + lg * 4;
#pragma unroll
            for (int r = 0; r < 4; r++) {
                float v = acc[i][j][r] + bv;
                if constexpr (EPI == 1) v = 0.5f * v * (1.f + erff(v * 0.70710678118654752f));
                const size_t o = (size_t)(grb + r) * N + gc;
                if constexpr (EPI == 3) outf[o] = v;
                else                    outb[o] = f2b(v);
            }
        }
    }
}

// ---------------------------------------------------------------------------
// 64x128 GEMM body (skinny-N occupancy), 4 waves of 64x32.
// lda/ldb = row strides, kc = K-chunk length for this block.
// EPI: 0 = bias->bf16, 4 = f32 partial (no bias, split-K)
// ---------------------------------------------------------------------------
template <int EPI>
__device__ __forceinline__ void gemm64(
    const u16* __restrict__ A, int lda, const u16* __restrict__ Bt, int ldb,
    const float* __restrict__ bias,
    float* __restrict__ outf, u16* __restrict__ outb,
    int M, int N, int kc, int bm, int bn)
{
    __shared__ u16 lsA[2][64 * 32];
    __shared__ u16 lsB[2][128 * 32];
    const int tid  = threadIdx.x;
    const int w    = tid >> 6, lane = tid & 63;
    const int lr   = lane & 15, lg = lane >> 4;
    const int m0   = bm * 64, n0 = bn * 128;
    const int wc   = w * 32;
    f32x4 acc[4][2] = {};

    const int row0 = tid >> 2;
    const int ksw8 = ((lane & 3) ^ ((lane >> 3) & 3)) * 8;
    const u16* a0  = A  + (size_t)(m0 + row0) * lda + ksw8;
    const u16* b0p = Bt + (size_t)(n0 + row0) * ldb + ksw8;
    const u16* b1p = b0p + (size_t)64 * ldb;
    const int rsw  = (lg ^ ((lr >> 1) & 3)) * 8;

    auto stage = [&](int buf, int ko) {
        char* la = (char*)lsA[buf] + w * 1024;
        char* lb = (char*)lsB[buf] + w * 1024;
        gload16(a0 + ko, la);
        gload16(b0p + ko, lb);
        gload16(b1p + ko, lb + 4096);
    };
    auto compute = [&](int buf) {
        bf16x8 af[4], bfv[2];
#pragma unroll
        for (int i = 0; i < 4; i++)
            af[i] = *(const bf16x8*)&lsA[buf][(i * 16 + lr) * 32 + rsw];
#pragma unroll
        for (int j = 0; j < 2; j++)
            bfv[j] = *(const bf16x8*)&lsB[buf][(wc + j * 16 + lr) * 32 + rsw];
#pragma unroll
        for (int i = 0; i < 4; i++)
#pragma unroll
            for (int j = 0; j < 2; j++)
                acc[i][j] = mfma16(af[i], bfv[j], acc[i][j]);
    };

    const int nk = kc >> 5;
    stage(0, 0);
    __syncthreads();
    int cur = 0;
    for (int kt = 0; kt < nk - 1; ++kt) {
        stage(cur ^ 1, (kt + 1) * 32);
        compute(cur);
        __syncthreads();
        cur ^= 1;
    }
    compute(cur);

#pragma unroll
    for (int j = 0; j < 2; j++) {
        const int gc = n0 + wc + j * 16 + lr;
        float bv = 0.f;
        if constexpr (EPI == 0) bv = bias[gc];
#pragma unroll
        for (int i = 0; i < 4; i++) {
            const int grb = m0 + i * 16 + lg * 4;
#pragma unroll
            for (int r = 0; r < 4; r++) {
                float v = acc[i][j][r] + bv;
                const size_t o = (size_t)(grb + r) * N + gc;
                if constexpr (EPI == 4) outf[o] = v;
                else                    outb[o] = f2b(v);
            }
        }
    }
}

__global__ __launch_bounds__(256) void gemm64_bias_k(
    const u16* A, const u16* Bt, const float* bias, u16* out, int M, int N, int K, int nbm)
{
    int2 b = swz_bmbn(nbm);
    gemm64<0>(A, K, Bt, K, bias, nullptr, out, M, N, K, b.x, b.y);
}
// split-K partial: blockIdx.y = k-chunk; partials at pbuf + s*M*N
__global__ __launch_bounds__(256) void gemm64_splitk_k(
    const u16* A, const u16* Bt, float* pbuf, int M, int N, int K, int kc, int nbm)
{
    int2 b = swz_bmbn(nbm);
    const int s = blockIdx.y;
    gemm64<4>(A + (size_t)s * kc, K, Bt + (size_t)s * kc, K, nullptr,
              pbuf + (size_t)s * M * N, nullptr, M, N, kc, b.x, b.y);
}
__global__ __launch_bounds__(256) void gemm128_gelu_k(
    const u16* A, const u16* Bt, const float* bias, u16* out, int M, int N, int K, int nbm)
{
    int2 b = swz_bmbn(nbm);
    gemm128<1>(A, Bt, bias, nullptr, out, M, N, K, b.x, b.y);
}
__global__ __launch_bounds__(256) void gemm128_plain_k(
    const u16* A, const u16* Bt, float* out, int M, int N, int K, int nbm)
{
    int2 b = swz_bmbn(nbm);
    gemm128<3>(A, Bt, nullptr, out, nullptr, M, N, K, b.x, b.y);
}

// ---------------------------------------------------------------------------
// Split-K reduce + residual + bias, fused with the FOLLOWING LayerNorm.
// x[row] += bias + sum_s pbuf[s][row]; hb = LN(x[row]; g, bln). One block/row.
// ---------------------------------------------------------------------------
__global__ __launch_bounds__(256) void reduce_ln_k(
    const float* __restrict__ pbuf, int S,
    const float* __restrict__ bias,
    float* __restrict__ x,
    const float* __restrict__ g, const float* __restrict__ bln,
    u16* __restrict__ hb)
{
    __shared__ float red[8];
    const int row = blockIdx.x, tid = threadIdx.x;
    const int w = tid >> 6, lane = tid & 63;
    const size_t base = (size_t)row * 256 + tid;
    float4 v = ((const float4*)x)[base];
    for (int s = 0; s < S; ++s) {
        const float4 p = ((const float4*)pbuf)[(size_t)s * 524288 + base];
        v.x += p.x; v.y += p.y; v.z += p.z; v.w += p.w;
    }
    const float4 bb = ((const float4*)bias)[tid];
    v.x += bb.x; v.y += bb.y; v.z += bb.z; v.w += bb.w;
    ((float4*)x)[base] = v;

    float s1 = v.x + v.y + v.z + v.w;
#pragma unroll
    for (int d = 1; d < 64; d <<= 1) s1 += __shfl_xor(s1, d);
    if (lane == 0) red[w] = s1;
    __syncthreads();
    const float mu = (red[0] + red[1] + red[2] + red[3]) * (1.f / 1024.f);
    const float d0 = v.x - mu, d1 = v.y - mu, d2 = v.z - mu, d3 = v.w - mu;
    float s2 = d0 * d0 + d1 * d1 + d2 * d2 + d3 * d3;
#pragma unroll
    for (int d = 1; d < 64; d <<= 1) s2 += __shfl_xor(s2, d);
    if (lane == 0) red[4 + w] = s2;
    __syncthreads();
    const float var = (red[4] + red[5] + red[6] + red[7]) * (1.f / 1024.f);
    const float rs = rsqrtf(var + 1e-5f);
    const float4 gv = ((const float4*)g)[tid];
    const float4 bv = ((const float4*)bln)[tid];
    u32 p0 = (u32)f2b(d0 * rs * gv.x + bv.x) | ((u32)f2b(d1 * rs * gv.y + bv.y) << 16);
    u32 p1 = (u32)f2b(d2 * rs * gv.z + bv.z) | ((u32)f2b(d3 * rs * gv.w + bv.w) << 16);
    ((uint2*)(hb + (size_t)row * 1024))[tid] = make_uint2(p0, p1);
}

// ---------------------------------------------------------------------------
// Flash attention, swapped-operand 32x32x16 structure (m214 port).
// ---------------------------------------------------------------------------
__global__ __launch_bounds__(256) void flash_attn_k(
    const u16* __restrict__ qkv, const u16* __restrict__ vT, u16* __restrict__ out)
{
    constexpr int DS = 3072, T = 2048;
    __shared__ float mrg[2][64][32];
    __shared__ float msh[2][32], lsh[2][32];
    __shared__ u16   sbuf[2][32 * 68];
    const int w = threadIdx.x >> 6, lane = threadIdx.x & 63;
    const int lq = lane & 31, hi = lane >> 5;
    const int hoff = blockIdx.y * 64;
    const int pair = w >> 1, par = w & 1;
    const int qt = (pair == 0) ? blockIdx.x : 63 - blockIdx.x;
    const int q0 = qt * 32;
    const int qg = q0 + lq;

    const u16* qp = qkv + (size_t)qg * DS + hoff;
    const u16* kp = qkv + 1024 + hoff;

    bf16x8 qf[4];
#pragma unroll
    for (int d = 0; d < 4; d++)
        qf[d] = *(const bf16x8*)(qp + d * 16 + hi * 8);

    f32x16 o0 = {}, o1 = {};
    float m_r = -1e30f, l_r = 0.f;

    const int ntiles = (qt >> 1) + 1;
    for (int t = par; t < ntiles; t += 2) {
        const int kv0 = t * 64;
        f32x16 s0 = {}, s1 = {};
        {
            const u16* kb0 = kp + (size_t)(kv0 + lq) * DS + hi * 8;
            const u16* kb1 = kb0 + (size_t)32 * DS;
#pragma unroll
            for (int d = 0; d < 4; d++) {
                s0 = mfma32(*(const bf16x8*)(kb0 + d * 16), qf[d], s0);
                s1 = mfma32(*(const bf16x8*)(kb1 + d * 16), qf[d], s1);
            }
        }
        float p[32];
        float mx = -1e30f;
#pragma unroll
        for (int r = 0; r < 16; r++) {
            const int kvl = (r & 3) + 8 * (r >> 2) + 4 * hi;
            float v0 = (kv0 + kvl      <= qg) ? s0[r] * 0.125f : -1e30f;
            float v1 = (kv0 + 32 + kvl <= qg) ? s1[r] * 0.125f : -1e30f;
            p[r] = v0; p[16 + r] = v1;
            mx = fmaxf(mx, fmaxf(v0, v1));
        }
        mx = fmaxf(mx, __shfl_xor(mx, 32));
        const float mn = fmaxf(m_r, mx);
        const float alpha = __expf(m_r - mn);
        m_r = mn;
        float ls = 0.f;
#pragma unroll
        for (int i = 0; i < 32; i++) { p[i] = __expf(p[i] - mn); ls += p[i]; }
        ls += __shfl_xor(ls, 32);
        l_r = l_r * alpha + ls;
#pragma unroll
        for (int r = 0; r < 16; r++) { o0[r] *= alpha; o1[r] *= alpha; }
#pragma unroll
        for (int sub = 0; sub < 2; sub++) {
            u32 pw[8], x[8];
#pragma unroll
            for (int i = 0; i < 8; i++)
                pw[i] = (u32)f2b(p[sub * 16 + 2 * i]) | ((u32)f2b(p[sub * 16 + 2 * i + 1]) << 16);
#pragma unroll
            for (int i = 0; i < 8; i++) x[i] = __shfl_xor(pw[i], 32);
            u32 b0[4], b1[4];
            b0[0] = hi ? x[2]  : pw[0];  b0[1] = hi ? x[3]  : pw[1];
            b0[2] = hi ? pw[2] : x[0];   b0[3] = hi ? pw[3] : x[1];
            b1[0] = hi ? x[6]  : pw[4];  b1[1] = hi ? x[7]  : pw[5];
            b1[2] = hi ? pw[6] : x[4];   b1[3] = hi ? pw[7] : x[5];
            bf16x8 B0 = __builtin_bit_cast(bf16x8, *(const uint4*)b0);
            bf16x8 B1 = __builtin_bit_cast(bf16x8, *(const uint4*)b1);
            const u16* vb = vT + (size_t)(hoff + lq) * T + kv0 + sub * 32 + hi * 8;
            o0 = mfma32(*(const bf16x8*)vb, B0, o0);
            o0 = mfma32(*(const bf16x8*)(vb + 16), B1, o0);
            const u16* vb1 = vb + (size_t)32 * T;
            o1 = mfma32(*(const bf16x8*)vb1, B0, o1);
            o1 = mfma32(*(const bf16x8*)(vb1 + 16), B1, o1);
        }
    }

    __syncthreads();
    if (par == 0) {
#pragma unroll
        for (int r = 0; r < 16; r++) {
            const int d = (r & 3) + 8 * (r >> 2) + 4 * hi;
            mrg[pair][d][lq]      = o0[r];
            mrg[pair][d + 32][lq] = o1[r];
        }
        if (hi == 0) { msh[pair][lq] = m_r; lsh[pair][lq] = l_r; }
    }
    __syncthreads();
    if (par == 1) {
        const float m0v = msh[pair][lq], l0v = lsh[pair][lq];
        const float M = fmaxf(m0v, m_r);
        const float f0 = __expf(m0v - M), f1 = __expf(m_r - M);
        const float linv = 1.f / (l0v * f0 + l_r * f1);
        u32* sb = (u32*)sbuf[pair];
#pragma unroll
        for (int r = 0; r < 16; r += 2) {
            const int d = (r & 3) + 8 * (r >> 2) + 4 * hi;
            float va = (mrg[pair][d][lq] * f0 + o0[r] * f1) * linv;
            float vb = (mrg[pair][d + 1][lq] * f0 + o0[r + 1] * f1) * linv;
            sb[lq * 34 + (d >> 1)] = (u32)f2b(va) | ((u32)f2b(vb) << 16);
            float vc = (mrg[pair][d + 32][lq] * f0 + o1[r] * f1) * linv;
            float vd = (mrg[pair][d + 33][lq] * f0 + o1[r + 1] * f1) * linv;
            sb[lq * 34 + ((d + 32) >> 1)] = (u32)f2b(vc) | ((u32)f2b(vd) << 16);
        }
#pragma unroll
        for (int ps = 0; ps < 8; ps++) {
            const int row = ps * 4 + (lane >> 4);
            const uint2 v = *(const uint2*)&sbuf[pair][row * 68 + (lane & 15) * 4];
            *(uint2*)(out + (size_t)(q0 + row) * 1024 + hoff + (lane & 15) * 4) = v;
        }
    }
}

// ---------------------------------------------------------------------------
__global__ __launch_bounds__(256) void transpose_cvt_k(
    const float* __restrict__ src, u16* __restrict__ dst, int K, int N,
    long long srcLS, long long dstLS)
{
    __shared__ float tile[32][33];
    src += (size_t)blockIdx.z * srcLS;
    dst += (size_t)blockIdx.z * dstLS;
    const int n0 = blockIdx.x * 32, k0 = blockIdx.y * 32;
    const int tx = threadIdx.x & 31, ty = threadIdx.x >> 5;
#pragma unroll
    for (int r = 0; r < 32; r += 8)
        tile[ty + r][tx] = src[(size_t)(k0 + ty + r) * N + n0 + tx];
    __syncthreads();
#pragma unroll
    for (int r = 0; r < 32; r += 8)
        dst[(size_t)(n0 + ty + r) * K + k0 + tx] = f2b(tile[tx][ty + r]);
}

__global__ __launch_bounds__(256) void transpose_u16_k(
    const u16* __restrict__ src, u16* __restrict__ dst, int R, int C, int srcStride)
{
    __shared__ u16 tile[32][33];
    const int c0 = blockIdx.x * 32, r0 = blockIdx.y * 32;
    const int tx = threadIdx.x & 31, ty = threadIdx.x >> 5;
#pragma unroll
    for (int r = 0; r < 32; r += 8)
        tile[ty + r][tx] = src[(size_t)(r0 + ty + r) * srcStride + c0 + tx];
    __syncthreads();
#pragma unroll
    for (int r = 0; r < 32; r += 8)
        dst[(size_t)(c0 + ty + r) * R + r0 + tx] = tile[tx][ty + r];
}

__global__ __launch_bounds__(256) void concat_bias_k(
    const float* __restrict__ bq, const float* __restrict__ bk,
    const float* __restrict__ bv, float* __restrict__ bcat)
{
    const int l = blockIdx.y;
    const int j = blockIdx.x * 256 + threadIdx.x;
    float v;
    if (j < 1024)      v = bq[l * 1024 + j];
    else if (j < 2048) v = bk[l * 1024 + j - 1024];
    else               v = bv[l * 1024 + j - 2048];
    bcat[l * 3072 + j] = v;
}

__global__ __launch_bounds__(256) void embed_pos_k(
    const int* __restrict__ idx, const float* __restrict__ emb, float* __restrict__ x)
{
    const int t = blockIdx.x, tid = threadIdx.x;
    const int tok = idx[t];
    float4 e = ((const float4*)(emb + (size_t)tok * 1024))[tid];
    const int d0 = tid * 4;
    const float c = -0.0089944730195080f;
    const float a0 = (float)t * expf((float)d0 * c);
    const float a1 = (float)t * expf((float)(d0 + 2) * c);
    e.x += sinf(a0); e.y += cosf(a0); e.z += sinf(a1); e.w += cosf(a1);
    ((float4*)(x + (size_t)t * 1024))[tid] = e;
}

__global__ __launch_bounds__(256) void layernorm_k(
    const float* __restrict__ x, const float* __restrict__ g,
    const float* __restrict__ b, u16* __restrict__ out)
{
    __shared__ float red[8];
    const int row = blockIdx.x, tid = threadIdx.x;
    const int w = tid >> 6, lane = tid & 63;
    const float4 v = ((const float4*)(x + (size_t)row * 1024))[tid];
    float s = v.x + v.y + v.z + v.w;
#pragma unroll
    for (int d = 1; d < 64; d <<= 1) s += __shfl_xor(s, d);
    if (lane == 0) red[w] = s;
    __syncthreads();
    const float mu = (red[0] + red[1] + red[2] + red[3]) * (1.f / 1024.f);
    const float d0 = v.x - mu, d1 = v.y - mu, d2 = v.z - mu, d3 = v.w - mu;
    float s2 = d0 * d0 + d1 * d1 + d2 * d2 + d3 * d3;
#pragma unroll
    for (int d = 1; d < 64; d <<= 1) s2 += __shfl_xor(s2, d);
    if (lane == 0) red[4 + w] = s2;
    __syncthreads();
    const float var = (red[4] + red[5] + red[6] + red[7]) * (1.f / 1024.f);
    const float rs = rsqrtf(var + 1e-5f);
    const float4 gv = ((const float4*)g)[tid];
    const float4 bv = ((const float4*)b)[tid];
    u32 p0 = (u32)f2b(d0 * rs * gv.x + bv.x) | ((u32)f2b(d1 * rs * gv.y + bv.y) << 16);
    u32 p1 = (u32)f2b(d2 * rs * gv.z + bv.z) | ((u32)f2b(d3 * rs * gv.w + bv.w) << 16);
    ((uint2*)(out + (size_t)row * 1024))[tid] = make_uint2(p0, p1);
}

// ---------------------------------------------------------------------------
extern "C" void kernel_launch(void* const* d_in, const int* in_sizes, int n_in,
                              void* d_out, int out_size, void* d_ws, size_t ws_size,
                              hipStream_t stream)
{
    const int*   idx   = (const int*)  d_in[0];
    const float* embed = (const float*)d_in[1];
    const float* Wq    = (const float*)d_in[2];
    const float* Wk    = (const float*)d_in[3];
    const float* Wv    = (const float*)d_in[4];
    const float* Wo    = (const float*)d_in[5];
    const float* bq    = (const float*)d_in[6];
    const float* bk    = (const float*)d_in[7];
    const float* bv    = (const float*)d_in[8];
    const float* bo    = (const float*)d_in[9];
    const float* ln1g  = (const float*)d_in[10];
    const float* ln1b  = (const float*)d_in[11];
    const float* ln2g  = (const float*)d_in[12];
    const float* ln2b  = (const float*)d_in[13];
    const float* w1    = (const float*)d_in[14];
    const float* b1    = (const float*)d_in[15];
    const float* w2    = (const float*)d_in[16];
    const float* b2    = (const float*)d_in[17];
    const float* lnfg  = (const float*)d_in[18];
    const float* lnfb  = (const float*)d_in[19];
    const float* headw = (const float*)d_in[20];

    char* ws = (char*)d_ws;
    auto alloc = [&](size_t bytes) {
        char* p = ws;
        ws += (bytes + 255) & ~(size_t)255;
        return p;
    };
    u16*   qkvT = (u16*)alloc((size_t)4 * 3072 * 1024 * 2);
    u16*   WoT  = (u16*)alloc((size_t)4 * 1024 * 1024 * 2);
    u16*   w1T  = (u16*)alloc((size_t)4 * 1024 * 4096 * 2);
    u16*   w2T  = (u16*)alloc((size_t)4 * 1024 * 4096 * 2);
    u16*   hT   = (u16*)alloc((size_t)32000 * 1024 * 2);
    float* bcat = (float*)alloc((size_t)4 * 3072 * 4);
    float* x    = (float*)alloc((size_t)2048 * 1024 * 4);
    u16*   hb   = (u16*)alloc((size_t)2048 * 1024 * 2);
    u16*   qkvb = (u16*)alloc((size_t)2048 * 3072 * 2);
    u16*   vTb  = (u16*)alloc((size_t)2048 * 1024 * 2);
    u16*   ab   = (u16*)alloc((size_t)2048 * 1024 * 2);
    u16*   ff   = (u16*)alloc((size_t)2048 * 4096 * 2);
    // split-K partial buffer: reuse d_out (262 MB, fully overwritten by head GEMM)
    float* pbuf = (float*)d_out;

    transpose_cvt_k<<<dim3(32, 32, 4),  256, 0, stream>>>(Wq, qkvT,            1024, 1024, 1048576, 3145728);
    transpose_cvt_k<<<dim3(32, 32, 4),  256, 0, stream>>>(Wk, qkvT + 1048576,  1024, 1024, 1048576, 3145728);
    transpose_cvt_k<<<dim3(32, 32, 4),  256, 0, stream>>>(Wv, qkvT + 2097152,  1024, 1024, 1048576, 3145728);
    transpose_cvt_k<<<dim3(32, 32, 4),  256, 0, stream>>>(Wo, WoT,             1024, 1024, 1048576, 1048576);
    transpose_cvt_k<<<dim3(128, 32, 4), 256, 0, stream>>>(w1, w1T,             1024, 4096, 4194304, 4194304);
    transpose_cvt_k<<<dim3(32, 128, 4), 256, 0, stream>>>(w2, w2T,             4096, 1024, 4194304, 4194304);
    transpose_cvt_k<<<dim3(1000, 32, 1), 256, 0, stream>>>(headw, hT,          1024, 32000, 0, 0);
    concat_bias_k<<<dim3(12, 4), 256, 0, stream>>>(bq, bk, bv, bcat);

    embed_pos_k<<<dim3(2048), 256, 0, stream>>>(idx, embed, x);
    layernorm_k<<<dim3(2048), 256, 0, stream>>>(x, ln1g, ln1b, hb);   // ln1 of layer 0

    for (int l = 0; l < 4; ++l) {
        // hb holds ln1(x) on loop entry
        gemm64_bias_k<<<dim3(768), 256, 0, stream>>>(hb, qkvT + (size_t)l * 3145728,
                                                     bcat + l * 3072, qkvb, 2048, 3072, 1024, 32);
        transpose_u16_k<<<dim3(32, 64), 256, 0, stream>>>(qkvb + 2048, vTb, 2048, 1024, 3072);
        flash_attn_k<<<dim3(32, 16), 256, 0, stream>>>(qkvb, vTb, ab);
        // o-proj split-K=2 -> pbuf; reduce fuses residual + ln2 -> x, hb
        gemm64_splitk_k<<<dim3(256, 2), 256, 0, stream>>>(ab, WoT + (size_t)l * 1048576,
                                                          pbuf, 2048, 1024, 1024, 512, 32);
        reduce_ln_k<<<dim3(2048), 256, 0, stream>>>(pbuf, 2, bo + l * 1024, x,
                                                    ln2g + l * 1024, ln2b + l * 1024, hb);
        gemm128_gelu_k<<<dim3(512), 256, 0, stream>>>(hb, w1T + (size_t)l * 4194304,
                                                      b1 + l * 4096, ff, 2048, 4096, 1024, 16);
        // ffn2 split-K=4 -> pbuf; reduce fuses residual + next LN (ln1_{l+1} or lnf)
        gemm64_splitk_k<<<dim3(256, 4), 256, 0, stream>>>(ff, w2T + (size_t)l * 4194304,
                                                          pbuf, 2048, 1024, 4096, 1024, 32);
        const float* ng = (l < 3) ? (ln1g + (l + 1) * 1024) : lnfg;
        const float* nb = (l < 3) ? (ln1b + (l + 1) * 1024) : lnfb;
        reduce_ln_k<<<dim3(2048), 256, 0, stream>>>(pbuf, 4, b2 + l * 1024, x, ng, nb, hb);
    }
    // hb holds lnf(x); head GEMM overwrites d_out (pbuf no longer needed)
    gemm128_plain_k<<<dim3(4000), 256, 0, stream>>>(hb, hT, (float*)d_out, 2048, 32000, 1024, 16);
}

// Round 5
// 1059.964 us; speedup vs baseline: 1.6309x; 1.0271x over previous
//
#include <hip/hip_runtime.h>
#include <cstdint>

using u16 = unsigned short;
using u32 = unsigned int;
typedef __bf16  bf16x8 __attribute__((ext_vector_type(8)));
typedef float   f32x4  __attribute__((ext_vector_type(4)));
typedef float   f32x16 __attribute__((ext_vector_type(16)));

__device__ __forceinline__ u16 f2b(float x) {
    u32 u = __builtin_bit_cast(u32, x);
    u = (u + 0x7fffu + ((u >> 16) & 1u)) >> 16;
    return (u16)u;
}

__device__ __forceinline__ f32x4 mfma16(bf16x8 a, bf16x8 b, f32x4 c) {
    return __builtin_amdgcn_mfma_f32_16x16x32_bf16(a, b, c, 0, 0, 0);
}
__device__ __forceinline__ f32x16 mfma32(bf16x8 a, bf16x8 b, f32x16 c) {
    return __builtin_amdgcn_mfma_f32_32x32x16_bf16(a, b, c, 0, 0, 0);
}

__device__ __forceinline__ void gload16(const void* g, void* lds) {
    auto gp = (__attribute__((address_space(1))) void*)(uintptr_t)g;
    auto lp = (__attribute__((address_space(3))) void*)(uintptr_t)lds;
    __builtin_amdgcn_global_load_lds(gp, lp, 16, 0, 0);
}

// bijective XCD-aware swizzle (m204); bm fastest so co-resident blocks share B panels
__device__ __forceinline__ int2 swz_bmbn(int nbm) {
    const int nwg = gridDim.x, orig = blockIdx.x;
    const int q = nwg >> 3, r = nwg & 7;
    const int xcd = orig & 7, lin = orig >> 3;
    const int id = (xcd < r ? xcd * (q + 1) : r * (q + 1) + (xcd - r) * q) + lin;
    return make_int2(id % nbm, id / nbm);
}

// ---------------------------------------------------------------------------
// 256x256 deep-pipelined GEMM (8-wave, BK=64 as 2 half-slots of 32k, ring of 4
// half-slots, counted vmcnt never 0 in steady state, setprio around MFMA).
// A [M,K], Bt [N,K] bf16 row-major; out f32 [M,N]. K % 64 == 0, M,N % 256 == 0.
// ---------------------------------------------------------------------------
__global__ __launch_bounds__(512, 2) void gemm256_head_k(
    const u16* __restrict__ A, const u16* __restrict__ Bt,
    float* __restrict__ out, int M, int N, int K)
{
    __shared__ __align__(16) u16 lsA[4][256 * 32];   // 64 KB
    __shared__ __align__(16) u16 lsB[4][256 * 32];   // 64 KB
    const int nbm = M >> 8;
    const int2 bb = swz_bmbn(nbm);
    const int m0 = bb.x * 256, n0 = bb.y * 256;
    const int tid = threadIdx.x;
    const int w = tid >> 6, lane = tid & 63;
    const int wr = (w >> 2) * 128, wc = (w & 3) * 64;
    const int lr = lane & 15, lg = lane >> 4;
    const int rsw = (lg ^ ((lr >> 1) & 3)) * 8;      // swizzled read k-offset (elems)

    const int trow = tid >> 2;                        // 0..127
    const int ksw8 = ((tid & 3) ^ ((tid >> 3) & 3)) * 8;
    const u16* aA = A  + (size_t)(m0 + trow) * K + ksw8;
    const u16* aB = Bt + (size_t)(n0 + trow) * K + ksw8;
    u16* dA = &lsA[0][0] + trow * 32 + (tid & 3) * 8; // + slot*8192 (+4096 for 2nd issue)
    u16* dB = &lsB[0][0] + trow * 32 + (tid & 3) * 8;

    f32x4 acc[8][4] = {};

    auto stage = [&](int h) {                         // stage half-step h into slot h&3
        const int s = h & 3;
        const int koff = h * 32;
        gload16(aA + koff,                 dA + s * 8192);
        gload16(aA + koff + (size_t)128 * K, dA + s * 8192 + 4096);
        gload16(aB + koff,                 dB + s * 8192);
        gload16(aB + koff + (size_t)128 * K, dB + s * 8192 + 4096);
    };

    const int H = K >> 5;                             // half-steps (32 for K=1024)
    stage(0); stage(1); stage(2);
    asm volatile("s_waitcnt vmcnt(8)" ::: "memory");  // slot 0 landed
    __builtin_amdgcn_s_barrier();

    for (int h = 0; h < H; ++h) {
        __builtin_amdgcn_sched_barrier(0);
        if (h + 3 < H) stage(h + 3);
        __builtin_amdgcn_sched_barrier(0);
        const int rem = H - 1 - h;                    // half-steps still in flight after slot h
        if (rem >= 3)      asm volatile("s_waitcnt vmcnt(12)" ::: "memory");
        else if (rem == 2) asm volatile("s_waitcnt vmcnt(8)"  ::: "memory");
        else if (rem == 1) asm volatile("s_waitcnt vmcnt(4)"  ::: "memory");
        else               asm volatile("s_waitcnt vmcnt(0)"  ::: "memory");
        __builtin_amdgcn_s_barrier();                 // slot h visible to all waves
        __builtin_amdgcn_sched_barrier(0);

        const int s = h & 3;
        bf16x8 af[8], bfv[4];
#pragma unroll
        for (int m = 0; m < 8; m++)
            af[m] = *(const bf16x8*)&lsA[s][(wr + m * 16 + lr) * 32 + rsw];
#pragma unroll
        for (int n = 0; n < 4; n++)
            bfv[n] = *(const bf16x8*)&lsB[s][(wc + n * 16 + lr) * 32 + rsw];

        __builtin_amdgcn_s_setprio(1);
#pragma unroll
        for (int m = 0; m < 8; m++)
#pragma unroll
            for (int n = 0; n < 4; n++)
                acc[m][n] = mfma16(af[m], bfv[n], acc[m][n]);
        __builtin_amdgcn_s_setprio(0);

        __builtin_amdgcn_sched_barrier(0);
        __builtin_amdgcn_s_barrier();                 // all waves done reading slot h
    }

#pragma unroll
    for (int m = 0; m < 8; m++) {
        const int gr = m0 + wr + m * 16 + lg * 4;
#pragma unroll
        for (int r = 0; r < 4; r++) {
            float* orow = out + (size_t)(gr + r) * N + n0 + wc + lr;
#pragma unroll
            for (int n = 0; n < 4; n++)
                orow[n * 16] = acc[m][n][r];
        }
    }
}

// ---------------------------------------------------------------------------
// 128x128 GEMM body, BK=32, dbuf LDS, k-slot XOR swizzle (2-way conflicts).
// EPI: 1 = bias+gelu->bf16
// ---------------------------------------------------------------------------
template <int EPI>
__device__ __forceinline__ void gemm128(
    const u16* __restrict__ A, const u16* __restrict__ Bt,
    const float* __restrict__ bias,
    float* __restrict__ outf, u16* __restrict__ outb,
    int M, int N, int K, int bm, int bn)
{
    __shared__ u16 lsA[2][128 * 32];
    __shared__ u16 lsB[2][128 * 32];
    const int tid  = threadIdx.x;
    const int w    = tid >> 6, lane = tid & 63;
    const int lr   = lane & 15, lg = lane >> 4;
    const int m0   = bm * 128, n0 = bn * 128;
    const int wr   = (w >> 1) * 64, wc = (w & 1) * 64;
    f32x4 acc[4][4] = {};

    const int row0 = tid >> 2;
    const int ksw8 = ((lane & 3) ^ ((lane >> 3) & 3)) * 8;
    const u16* a0  = A  + (size_t)(m0 + row0) * K + ksw8;
    const u16* a1  = a0 + (size_t)64 * K;
    const u16* b0p = Bt + (size_t)(n0 + row0) * K + ksw8;
    const u16* b1p = b0p + (size_t)64 * K;
    const int rsw  = (lg ^ ((lr >> 1) & 3)) * 8;

    auto stage = [&](int buf, int ko) {
        char* la = (char*)lsA[buf] + w * 1024;
        char* lb = (char*)lsB[buf] + w * 1024;
        gload16(a0 + ko, la);
        gload16(a1 + ko, la + 4096);
        gload16(b0p + ko, lb);
        gload16(b1p + ko, lb + 4096);
    };
    auto compute = [&](int buf) {
        bf16x8 af[4], bfv[4];
#pragma unroll
        for (int i = 0; i < 4; i++)
            af[i] = *(const bf16x8*)&lsA[buf][(wr + i * 16 + lr) * 32 + rsw];
#pragma unroll
        for (int j = 0; j < 4; j++)
            bfv[j] = *(const bf16x8*)&lsB[buf][(wc + j * 16 + lr) * 32 + rsw];
#pragma unroll
        for (int i = 0; i < 4; i++)
#pragma unroll
            for (int j = 0; j < 4; j++)
                acc[i][j] = mfma16(af[i], bfv[j], acc[i][j]);
    };

    const int nk = K >> 5;
    stage(0, 0);
    __syncthreads();
    int cur = 0;
    for (int kt = 0; kt < nk - 1; ++kt) {
        stage(cur ^ 1, (kt + 1) * 32);
        compute(cur);
        __syncthreads();
        cur ^= 1;
    }
    compute(cur);

#pragma unroll
    for (int j = 0; j < 4; j++) {
        const int gc = n0 + wc + j * 16 + lr;
        const float bv = bias[gc];
#pragma unroll
        for (int i = 0; i < 4; i++) {
            const int grb = m0 + wr + i * 16 + lg * 4;
#pragma unroll
            for (int r = 0; r < 4; r++) {
                float v = acc[i][j][r] + bv;
                if constexpr (EPI == 1) v = 0.5f * v * (1.f + erff(v * 0.70710678118654752f));
                outb[(size_t)(grb + r) * N + gc] = f2b(v);
            }
        }
    }
}

// ---------------------------------------------------------------------------
// 64x128 GEMM body (skinny-N occupancy), 4 waves of 64x32.
// EPI: 0 = bias->bf16, 4 = f32 partial (no bias, split-K)
// ---------------------------------------------------------------------------
template <int EPI>
__device__ __forceinline__ void gemm64(
    const u16* __restrict__ A, int lda, const u16* __restrict__ Bt, int ldb,
    const float* __restrict__ bias,
    float* __restrict__ outf, u16* __restrict__ outb,
    int M, int N, int kc, int bm, int bn)
{
    __shared__ u16 lsA[2][64 * 32];
    __shared__ u16 lsB[2][128 * 32];
    const int tid  = threadIdx.x;
    const int w    = tid >> 6, lane = tid & 63;
    const int lr   = lane & 15, lg = lane >> 4;
    const int m0   = bm * 64, n0 = bn * 128;
    const int wc   = w * 32;
    f32x4 acc[4][2] = {};

    const int row0 = tid >> 2;
    const int ksw8 = ((lane & 3) ^ ((lane >> 3) & 3)) * 8;
    const u16* a0  = A  + (size_t)(m0 + row0) * lda + ksw8;
    const u16* b0p = Bt + (size_t)(n0 + row0) * ldb + ksw8;
    const u16* b1p = b0p + (size_t)64 * ldb;
    const int rsw  = (lg ^ ((lr >> 1) & 3)) * 8;

    auto stage = [&](int buf, int ko) {
        char* la = (char*)lsA[buf] + w * 1024;
        char* lb = (char*)lsB[buf] + w * 1024;
        gload16(a0 + ko, la);
        gload16(b0p + ko, lb);
        gload16(b1p + ko, lb + 4096);
    };
    auto compute = [&](int buf) {
        bf16x8 af[4], bfv[2];
#pragma unroll
        for (int i = 0; i < 4; i++)
            af[i] = *(const bf16x8*)&lsA[buf][(i * 16 + lr) * 32 + rsw];
#pragma unroll
        for (int j = 0; j < 2; j++)
            bfv[j] = *(const bf16x8*)&lsB[buf][(wc + j * 16 + lr) * 32 + rsw];
#pragma unroll
        for (int i = 0; i < 4; i++)
#pragma unroll
            for (int j = 0; j < 2; j++)
                acc[i][j] = mfma16(af[i], bfv[j], acc[i][j]);
    };

    const int nk = kc >> 5;
    stage(0, 0);
    __syncthreads();
    int cur = 0;
    for (int kt = 0; kt < nk - 1; ++kt) {
        stage(cur ^ 1, (kt + 1) * 32);
        compute(cur);
        __syncthreads();
        cur ^= 1;
    }
    compute(cur);

#pragma unroll
    for (int j = 0; j < 2; j++) {
        const int gc = n0 + wc + j * 16 + lr;
        float bv = 0.f;
        if constexpr (EPI == 0) bv = bias[gc];
#pragma unroll
        for (int i = 0; i < 4; i++) {
            const int grb = m0 + i * 16 + lg * 4;
#pragma unroll
            for (int r = 0; r < 4; r++) {
                float v = acc[i][j][r] + bv;
                const size_t o = (size_t)(grb + r) * N + gc;
                if constexpr (EPI == 4) outf[o] = v;
                else                    outb[o] = f2b(v);
            }
        }
    }
}

__global__ __launch_bounds__(256) void gemm64_bias_k(
    const u16* A, const u16* Bt, const float* bias, u16* out, int M, int N, int K, int nbm)
{
    int2 b = swz_bmbn(nbm);
    gemm64<0>(A, K, Bt, K, bias, nullptr, out, M, N, K, b.x, b.y);
}
__global__ __launch_bounds__(256) void gemm64_splitk_k(
    const u16* A, const u16* Bt, float* pbuf, int M, int N, int K, int kc, int nbm)
{
    int2 b = swz_bmbn(nbm);
    const int s = blockIdx.y;
    gemm64<4>(A + (size_t)s * kc, K, Bt + (size_t)s * kc, K, nullptr,
              pbuf + (size_t)s * M * N, nullptr, M, N, kc, b.x, b.y);
}
__global__ __launch_bounds__(256) void gemm128_gelu_k(
    const u16* A, const u16* Bt, const float* bias, u16* out, int M, int N, int K, int nbm)
{
    int2 b = swz_bmbn(nbm);
    gemm128<1>(A, Bt, bias, nullptr, out, M, N, K, b.x, b.y);
}

// ---------------------------------------------------------------------------
// Split-K reduce + residual + bias, fused with the FOLLOWING LayerNorm.
// ---------------------------------------------------------------------------
__global__ __launch_bounds__(256) void reduce_ln_k(
    const float* __restrict__ pbuf, int S,
    const float* __restrict__ bias,
    float* __restrict__ x,
    const float* __restrict__ g, const float* __restrict__ bln,
    u16* __restrict__ hb)
{
    __shared__ float red[8];
    const int row = blockIdx.x, tid = threadIdx.x;
    const int w = tid >> 6, lane = tid & 63;
    const size_t base = (size_t)row * 256 + tid;
    float4 v = ((const float4*)x)[base];
    for (int s = 0; s < S; ++s) {
        const float4 p = ((const float4*)pbuf)[(size_t)s * 524288 + base];
        v.x += p.x; v.y += p.y; v.z += p.z; v.w += p.w;
    }
    const float4 bb = ((const float4*)bias)[tid];
    v.x += bb.x; v.y += bb.y; v.z += bb.z; v.w += bb.w;
    ((float4*)x)[base] = v;

    float s1 = v.x + v.y + v.z + v.w;
#pragma unroll
    for (int d = 1; d < 64; d <<= 1) s1 += __shfl_xor(s1, d);
    if (lane == 0) red[w] = s1;
    __syncthreads();
    const float mu = (red[0] + red[1] + red[2] + red[3]) * (1.f / 1024.f);
    const float d0 = v.x - mu, d1 = v.y - mu, d2 = v.z - mu, d3 = v.w - mu;
    float s2 = d0 * d0 + d1 * d1 + d2 * d2 + d3 * d3;
#pragma unroll
    for (int d = 1; d < 64; d <<= 1) s2 += __shfl_xor(s2, d);
    if (lane == 0) red[4 + w] = s2;
    __syncthreads();
    const float var = (red[4] + red[5] + red[6] + red[7]) * (1.f / 1024.f);
    const float rs = rsqrtf(var + 1e-5f);
    const float4 gv = ((const float4*)g)[tid];
    const float4 bv = ((const float4*)bln)[tid];
    u32 p0 = (u32)f2b(d0 * rs * gv.x + bv.x) | ((u32)f2b(d1 * rs * gv.y + bv.y) << 16);
    u32 p1 = (u32)f2b(d2 * rs * gv.z + bv.z) | ((u32)f2b(d3 * rs * gv.w + bv.w) << 16);
    ((uint2*)(hb + (size_t)row * 1024))[tid] = make_uint2(p0, p1);
}

// ---------------------------------------------------------------------------
// Flash attention, swapped-operand 32x32x16 structure (m214 port).
// ---------------------------------------------------------------------------
__global__ __launch_bounds__(256) void flash_attn_k(
    const u16* __restrict__ qkv, const u16* __restrict__ vT, u16* __restrict__ out)
{
    constexpr int DS = 3072, T = 2048;
    __shared__ float mrg[2][64][32];
    __shared__ float msh[2][32], lsh[2][32];
    __shared__ u16   sbuf[2][32 * 68];
    const int w = threadIdx.x >> 6, lane = threadIdx.x & 63;
    const int lq = lane & 31, hi = lane >> 5;
    const int hoff = blockIdx.y * 64;
    const int pair = w >> 1, par = w & 1;
    const int qt = (pair == 0) ? blockIdx.x : 63 - blockIdx.x;
    const int q0 = qt * 32;
    const int qg = q0 + lq;

    const u16* qp = qkv + (size_t)qg * DS + hoff;
    const u16* kp = qkv + 1024 + hoff;

    bf16x8 qf[4];
#pragma unroll
    for (int d = 0; d < 4; d++)
        qf[d] = *(const bf16x8*)(qp + d * 16 + hi * 8);

    f32x16 o0 = {}, o1 = {};
    float m_r = -1e30f, l_r = 0.f;

    const int ntiles = (qt >> 1) + 1;
    for (int t = par; t < ntiles; t += 2) {
        const int kv0 = t * 64;
        f32x16 s0 = {}, s1 = {};
        {
            const u16* kb0 = kp + (size_t)(kv0 + lq) * DS + hi * 8;
            const u16* kb1 = kb0 + (size_t)32 * DS;
#pragma unroll
            for (int d = 0; d < 4; d++) {
                s0 = mfma32(*(const bf16x8*)(kb0 + d * 16), qf[d], s0);
                s1 = mfma32(*(const bf16x8*)(kb1 + d * 16), qf[d], s1);
            }
        }
        float p[32];
        float mx = -1e30f;
#pragma unroll
        for (int r = 0; r < 16; r++) {
            const int kvl = (r & 3) + 8 * (r >> 2) + 4 * hi;
            float v0 = (kv0 + kvl      <= qg) ? s0[r] * 0.125f : -1e30f;
            float v1 = (kv0 + 32 + kvl <= qg) ? s1[r] * 0.125f : -1e30f;
            p[r] = v0; p[16 + r] = v1;
            mx = fmaxf(mx, fmaxf(v0, v1));
        }
        mx = fmaxf(mx, __shfl_xor(mx, 32));
        const float mn = fmaxf(m_r, mx);
        const float alpha = __expf(m_r - mn);
        m_r = mn;
        float ls = 0.f;
#pragma unroll
        for (int i = 0; i < 32; i++) { p[i] = __expf(p[i] - mn); ls += p[i]; }
        ls += __shfl_xor(ls, 32);
        l_r = l_r * alpha + ls;
#pragma unroll
        for (int r = 0; r < 16; r++) { o0[r] *= alpha; o1[r] *= alpha; }
#pragma unroll
        for (int sub = 0; sub < 2; sub++) {
            u32 pw[8], x[8];
#pragma unroll
            for (int i = 0; i < 8; i++)
                pw[i] = (u32)f2b(p[sub * 16 + 2 * i]) | ((u32)f2b(p[sub * 16 + 2 * i + 1]) << 16);
#pragma unroll
            for (int i = 0; i < 8; i++) x[i] = __shfl_xor(pw[i], 32);
            u32 b0[4], b1[4];
            b0[0] = hi ? x[2]  : pw[0];  b0[1] = hi ? x[3]  : pw[1];
            b0[2] = hi ? pw[2] : x[0];   b0[3] = hi ? pw[3] : x[1];
            b1[0] = hi ? x[6]  : pw[4];  b1[1] = hi ? x[7]  : pw[5];
            b1[2] = hi ? pw[6] : x[4];   b1[3] = hi ? pw[7] : x[5];
            bf16x8 B0 = __builtin_bit_cast(bf16x8, *(const uint4*)b0);
            bf16x8 B1 = __builtin_bit_cast(bf16x8, *(const uint4*)b1);
            const u16* vb = vT + (size_t)(hoff + lq) * T + kv0 + sub * 32 + hi * 8;
            o0 = mfma32(*(const bf16x8*)vb, B0, o0);
            o0 = mfma32(*(const bf16x8*)(vb + 16), B1, o0);
            const u16* vb1 = vb + (size_t)32 * T;
            o1 = mfma32(*(const bf16x8*)vb1, B0, o1);
            o1 = mfma32(*(const bf16x8*)(vb1 + 16), B1, o1);
        }
    }

    __syncthreads();
    if (par == 0) {
#pragma unroll
        for (int r = 0; r < 16; r++) {
            const int d = (r & 3) + 8 * (r >> 2) + 4 * hi;
            mrg[pair][d][lq]      = o0[r];
            mrg[pair][d + 32][lq] = o1[r];
        }
        if (hi == 0) { msh[pair][lq] = m_r; lsh[pair][lq] = l_r; }
    }
    __syncthreads();
    if (par == 1) {
        const float m0v = msh[pair][lq], l0v = lsh[pair][lq];
        const float M = fmaxf(m0v, m_r);
        const float f0 = __expf(m0v - M), f1 = __expf(m_r - M);
        const float linv = 1.f / (l0v * f0 + l_r * f1);
        u32* sb = (u32*)sbuf[pair];
#pragma unroll
        for (int r = 0; r < 16; r += 2) {
            const int d = (r & 3) + 8 * (r >> 2) + 4 * hi;
            float va = (mrg[pair][d][lq] * f0 + o0[r] * f1) * linv;
            float vb = (mrg[pair][d + 1][lq] * f0 + o0[r + 1] * f1) * linv;
            sb[lq * 34 + (d >> 1)] = (u32)f2b(va) | ((u32)f2b(vb) << 16);
            float vc = (mrg[pair][d + 32][lq] * f0 + o1[r] * f1) * linv;
            float vd = (mrg[pair][d + 33][lq] * f0 + o1[r + 1] * f1) * linv;
            sb[lq * 34 + ((d + 32) >> 1)] = (u32)f2b(vc) | ((u32)f2b(vd) << 16);
        }
#pragma unroll
        for (int ps = 0; ps < 8; ps++) {
            const int row = ps * 4 + (lane >> 4);
            const uint2 v = *(const uint2*)&sbuf[pair][row * 68 + (lane & 15) * 4];
            *(uint2*)(out + (size_t)(q0 + row) * 1024 + hoff + (lane & 15) * 4) = v;
        }
    }
}

// ---------------------------------------------------------------------------
__global__ __launch_bounds__(256) void transpose_cvt_k(
    const float* __restrict__ src, u16* __restrict__ dst, int K, int N,
    long long srcLS, long long dstLS)
{
    __shared__ float tile[32][33];
    src += (size_t)blockIdx.z * srcLS;
    dst += (size_t)blockIdx.z * dstLS;
    const int n0 = blockIdx.x * 32, k0 = blockIdx.y * 32;
    const int tx = threadIdx.x & 31, ty = threadIdx.x >> 5;
#pragma unroll
    for (int r = 0; r < 32; r += 8)
        tile[ty + r][tx] = src[(size_t)(k0 + ty + r) * N + n0 + tx];
    __syncthreads();
#pragma unroll
    for (int r = 0; r < 32; r += 8)
        dst[(size_t)(n0 + ty + r) * K + k0 + tx] = f2b(tile[tx][ty + r]);
}

__global__ __launch_bounds__(256) void transpose_u16_k(
    const u16* __restrict__ src, u16* __restrict__ dst, int R, int C, int srcStride)
{
    __shared__ u16 tile[32][33];
    const int c0 = blockIdx.x * 32, r0 = blockIdx.y * 32;
    const int tx = threadIdx.x & 31, ty = threadIdx.x >> 5;
#pragma unroll
    for (int r = 0; r < 32; r += 8)
        tile[ty + r][tx] = src[(size_t)(r0 + ty + r) * srcStride + c0 + tx];
    __syncthreads();
#pragma unroll
    for (int r = 0; r < 32; r += 8)
        dst[(size_t)(c0 + ty + r) * R + r0 + tx] = tile[tx][ty + r];
}

__global__ __launch_bounds__(256) void concat_bias_k(
    const float* __restrict__ bq, const float* __restrict__ bk,
    const float* __restrict__ bv, float* __restrict__ bcat)
{
    const int l = blockIdx.y;
    const int j = blockIdx.x * 256 + threadIdx.x;
    float v;
    if (j < 1024)      v = bq[l * 1024 + j];
    else if (j < 2048) v = bk[l * 1024 + j - 1024];
    else               v = bv[l * 1024 + j - 2048];
    bcat[l * 3072 + j] = v;
}

__global__ __launch_bounds__(256) void embed_pos_k(
    const int* __restrict__ idx, const float* __restrict__ emb, float* __restrict__ x)
{
    const int t = blockIdx.x, tid = threadIdx.x;
    const int tok = idx[t];
    float4 e = ((const float4*)(emb + (size_t)tok * 1024))[tid];
    const int d0 = tid * 4;
    const float c = -0.0089944730195080f;
    const float a0 = (float)t * expf((float)d0 * c);
    const float a1 = (float)t * expf((float)(d0 + 2) * c);
    e.x += sinf(a0); e.y += cosf(a0); e.z += sinf(a1); e.w += cosf(a1);
    ((float4*)(x + (size_t)t * 1024))[tid] = e;
}

__global__ __launch_bounds__(256) void layernorm_k(
    const float* __restrict__ x, const float* __restrict__ g,
    const float* __restrict__ b, u16* __restrict__ out)
{
    __shared__ float red[8];
    const int row = blockIdx.x, tid = threadIdx.x;
    const int w = tid >> 6, lane = tid & 63;
    const float4 v = ((const float4*)(x + (size_t)row * 1024))[tid];
    float s = v.x + v.y + v.z + v.w;
#pragma unroll
    for (int d = 1; d < 64; d <<= 1) s += __shfl_xor(s, d);
    if (lane == 0) red[w] = s;
    __syncthreads();
    const float mu = (red[0] + red[1] + red[2] + red[3]) * (1.f / 1024.f);
    const float d0 = v.x - mu, d1 = v.y - mu, d2 = v.z - mu, d3 = v.w - mu;
    float s2 = d0 * d0 + d1 * d1 + d2 * d2 + d3 * d3;
#pragma unroll
    for (int d = 1; d < 64; d <<= 1) s2 += __shfl_xor(s2, d);
    if (lane == 0) red[4 + w] = s2;
    __syncthreads();
    const float var = (red[4] + red[5] + red[6] + red[7]) * (1.f / 1024.f);
    const float rs = rsqrtf(var + 1e-5f);
    const float4 gv = ((const float4*)g)[tid];
    const float4 bv = ((const float4*)b)[tid];
    u32 p0 = (u32)f2b(d0 * rs * gv.x + bv.x) | ((u32)f2b(d1 * rs * gv.y + bv.y) << 16);
    u32 p1 = (u32)f2b(d2 * rs * gv.z + bv.z) | ((u32)f2b(d3 * rs * gv.w + bv.w) << 16);
    ((uint2*)(out + (size_t)row * 1024))[tid] = make_uint2(p0, p1);
}

// ---------------------------------------------------------------------------
extern "C" void kernel_launch(void* const* d_in, const int* in_sizes, int n_in,
                              void* d_out, int out_size, void* d_ws, size_t ws_size,
                              hipStream_t stream)
{
    const int*   idx   = (const int*)  d_in[0];
    const float* embed = (const float*)d_in[1];
    const float* Wq    = (const float*)d_in[2];
    const float* Wk    = (const float*)d_in[3];
    const float* Wv    = (const float*)d_in[4];
    const float* Wo    = (const float*)d_in[5];
    const float* bq    = (const float*)d_in[6];
    const float* bk    = (const float*)d_in[7];
    const float* bv    = (const float*)d_in[8];
    const float* bo    = (const float*)d_in[9];
    const float* ln1g  = (const float*)d_in[10];
    const float* ln1b  = (const float*)d_in[11];
    const float* ln2g  = (const float*)d_in[12];
    const float* ln2b  = (const float*)d_in[13];
    const float* w1    = (const float*)d_in[14];
    const float* b1    = (const float*)d_in[15];
    const float* w2    = (const float*)d_in[16];
    const float* b2    = (const float*)d_in[17];
    const float* lnfg  = (const float*)d_in[18];
    const float* lnfb  = (const float*)d_in[19];
    const float* headw = (const float*)d_in[20];

    char* ws = (char*)d_ws;
    auto alloc = [&](size_t bytes) {
        char* p = ws;
        ws += (bytes + 255) & ~(size_t)255;
        return p;
    };
    u16*   qkvT = (u16*)alloc((size_t)4 * 3072 * 1024 * 2);
    u16*   WoT  = (u16*)alloc((size_t)4 * 1024 * 1024 * 2);
    u16*   w1T  = (u16*)alloc((size_t)4 * 1024 * 4096 * 2);
    u16*   w2T  = (u16*)alloc((size_t)4 * 1024 * 4096 * 2);
    u16*   hT   = (u16*)alloc((size_t)32000 * 1024 * 2);
    float* bcat = (float*)alloc((size_t)4 * 3072 * 4);
    float* x    = (float*)alloc((size_t)2048 * 1024 * 4);
    u16*   hb   = (u16*)alloc((size_t)2048 * 1024 * 2);
    u16*   qkvb = (u16*)alloc((size_t)2048 * 3072 * 2);
    u16*   vTb  = (u16*)alloc((size_t)2048 * 1024 * 2);
    u16*   ab   = (u16*)alloc((size_t)2048 * 1024 * 2);
    u16*   ff   = (u16*)alloc((size_t)2048 * 4096 * 2);
    float* pbuf = (float*)d_out;   // split-K partials; head GEMM overwrites at the end

    transpose_cvt_k<<<dim3(32, 32, 4),  256, 0, stream>>>(Wq, qkvT,            1024, 1024, 1048576, 3145728);
    transpose_cvt_k<<<dim3(32, 32, 4),  256, 0, stream>>>(Wk, qkvT + 1048576,  1024, 1024, 1048576, 3145728);
    transpose_cvt_k<<<dim3(32, 32, 4),  256, 0, stream>>>(Wv, qkvT + 2097152,  1024, 1024, 1048576, 3145728);
    transpose_cvt_k<<<dim3(32, 32, 4),  256, 0, stream>>>(Wo, WoT,             1024, 1024, 1048576, 1048576);
    transpose_cvt_k<<<dim3(128, 32, 4), 256, 0, stream>>>(w1, w1T,             1024, 4096, 4194304, 4194304);
    transpose_cvt_k<<<dim3(32, 128, 4), 256, 0, stream>>>(w2, w2T,             4096, 1024, 4194304, 4194304);
    transpose_cvt_k<<<dim3(1000, 32, 1), 256, 0, stream>>>(headw, hT,          1024, 32000, 0, 0);
    concat_bias_k<<<dim3(12, 4), 256, 0, stream>>>(bq, bk, bv, bcat);

    embed_pos_k<<<dim3(2048), 256, 0, stream>>>(idx, embed, x);
    layernorm_k<<<dim3(2048), 256, 0, stream>>>(x, ln1g, ln1b, hb);

    for (int l = 0; l < 4; ++l) {
        gemm64_bias_k<<<dim3(768), 256, 0, stream>>>(hb, qkvT + (size_t)l * 3145728,
                                                     bcat + l * 3072, qkvb, 2048, 3072, 1024, 32);
        transpose_u16_k<<<dim3(32, 64), 256, 0, stream>>>(qkvb + 2048, vTb, 2048, 1024, 3072);
        flash_attn_k<<<dim3(32, 16), 256, 0, stream>>>(qkvb, vTb, ab);
        gemm64_splitk_k<<<dim3(256, 2), 256, 0, stream>>>(ab, WoT + (size_t)l * 1048576,
                                                          pbuf, 2048, 1024, 1024, 512, 32);
        reduce_ln_k<<<dim3(2048), 256, 0, stream>>>(pbuf, 2, bo + l * 1024, x,
                                                    ln2g + l * 1024, ln2b + l * 1024, hb);
        gemm128_gelu_k<<<dim3(512), 256, 0, stream>>>(hb, w1T + (size_t)l * 4194304,
                                                      b1 + l * 4096, ff, 2048, 4096, 1024, 16);
        gemm64_splitk_k<<<dim3(256, 4), 256, 0, stream>>>(ff, w2T + (size_t)l * 4194304,
                                                          pbuf, 2048, 1024, 4096, 1024, 32);
        const float* ng = (l < 3) ? (ln1g + (l + 1) * 1024) : lnfg;
        const float* nb = (l < 3) ? (ln1b + (l + 1) * 1024) : lnfb;
        reduce_ln_k<<<dim3(2048), 256, 0, stream>>>(pbuf, 4, b2 + l * 1024, x, ng, nb, hb);
    }
    // head: 256x256 deep-pipelined GEMM, grid = 8 x 125 = 1000 blocks of 512
    gemm256_head_k<<<dim3(1000), 512, 0, stream>>>(hb, hT, (float*)d_out, 2048, 32000, 1024);
}

// Round 6
// 1039.213 us; speedup vs baseline: 1.6634x; 1.0200x over previous
//
#include <hip/hip_runtime.h>
#include <cstdint>

using u16 = unsigned short;
using u32 = unsigned int;
typedef __bf16  bf16x8 __attribute__((ext_vector_type(8)));
typedef float   f32x4  __attribute__((ext_vector_type(4)));
typedef float   f32x16 __attribute__((ext_vector_type(16)));

__device__ __forceinline__ u16 f2b(float x) {
    u32 u = __builtin_bit_cast(u32, x);
    u = (u + 0x7fffu + ((u >> 16) & 1u)) >> 16;
    return (u16)u;
}

__device__ __forceinline__ f32x4 mfma16(bf16x8 a, bf16x8 b, f32x4 c) {
    return __builtin_amdgcn_mfma_f32_16x16x32_bf16(a, b, c, 0, 0, 0);
}
__device__ __forceinline__ f32x16 mfma32(bf16x8 a, bf16x8 b, f32x16 c) {
    return __builtin_amdgcn_mfma_f32_32x32x16_bf16(a, b, c, 0, 0, 0);
}

__device__ __forceinline__ void gload16(const void* g, void* lds) {
    auto gp = (__attribute__((address_space(1))) void*)(uintptr_t)g;
    auto lp = (__attribute__((address_space(3))) void*)(uintptr_t)lds;
    __builtin_amdgcn_global_load_lds(gp, lp, 16, 0, 0);
}

// bijective XCD-aware swizzle (m204); bm fastest so co-resident blocks share B panels
__device__ __forceinline__ int2 swz_bmbn(int nbm) {
    const int nwg = gridDim.x, orig = blockIdx.x;
    const int q = nwg >> 3, r = nwg & 7;
    const int xcd = orig & 7, lin = orig >> 3;
    const int id = (xcd < r ? xcd * (q + 1) : r * (q + 1) + (xcd - r) * q) + lin;
    return make_int2(id % nbm, id / nbm);
}

// ---------------------------------------------------------------------------
// 256x256 deep-pipelined GEMM, 8 waves. Ring of 4 half-slots (32k each).
// One-slot-ahead register pipeline: ds_reads for slot h+1 issue BEFORE the
// MFMA cluster of slot h (latency hides under MFMA). Counted vmcnt (8/4/0),
// single barrier per half-slot, setprio around MFMA.
// ---------------------------------------------------------------------------
template <int KV>
__global__ __launch_bounds__(512, 2) void gemm256_head_k(
    const u16* __restrict__ A, const u16* __restrict__ Bt,
    float* __restrict__ out, int M, int N)
{
    __shared__ __align__(16) u16 lsA[4][256 * 32];   // 64 KB
    __shared__ __align__(16) u16 lsB[4][256 * 32];   // 64 KB
    const int nbm = M >> 8;
    const int2 bb = swz_bmbn(nbm);
    const int m0 = bb.x * 256, n0 = bb.y * 256;
    const int tid = threadIdx.x;
    const int w = tid >> 6, lane = tid & 63;
    const int wr = (w >> 2) * 128, wc = (w & 3) * 64;
    const int lr = lane & 15, lg = lane >> 4;
    const int rsw = (lg ^ ((lr >> 1) & 3)) * 8;

    const int trow = tid >> 2;                        // 0..127
    const int ksw8 = ((tid & 3) ^ ((tid >> 3) & 3)) * 8;
    const u16* aA = A  + (size_t)(m0 + trow) * KV + ksw8;
    const u16* aB = Bt + (size_t)(n0 + trow) * KV + ksw8;
    u16* dA = &lsA[0][0] + trow * 32 + (tid & 3) * 8;
    u16* dB = &lsB[0][0] + trow * 32 + (tid & 3) * 8;

    f32x4 acc[8][4] = {};

    auto stage = [&](int h) {                         // stage half-step h into slot h&3
        const int s = h & 3;
        const int koff = h * 32;
        gload16(aA + koff,                    dA + s * 8192);
        gload16(aA + koff + (size_t)128 * KV, dA + s * 8192 + 4096);
        gload16(aB + koff,                    dB + s * 8192);
        gload16(aB + koff + (size_t)128 * KV, dB + s * 8192 + 4096);
    };

    bf16x8 ra0[8], rb0[4], ra1[8], rb1[4];            // two named reg sets (rule #20)
    auto lread = [&](bf16x8* af, bf16x8* bf, int h) {
        const int s = h & 3;
#pragma unroll
        for (int m = 0; m < 8; m++)
            af[m] = *(const bf16x8*)&lsA[s][(wr + m * 16 + lr) * 32 + rsw];
#pragma unroll
        for (int n = 0; n < 4; n++)
            bf[n] = *(const bf16x8*)&lsB[s][(wc + n * 16 + lr) * 32 + rsw];
    };
    auto mm = [&](bf16x8* af, bf16x8* bf) {
        __builtin_amdgcn_s_setprio(1);
#pragma unroll
        for (int m = 0; m < 8; m++)
#pragma unroll
            for (int n = 0; n < 4; n++)
                acc[m][n] = mfma16(af[m], bf[n], acc[m][n]);
        __builtin_amdgcn_s_setprio(0);
    };
    // body(h): stage h+3; lgkm0 (slot-h regs ready -> barrier-safe overwrite of
    // slot h-1 next iter); counted vmcnt (slot h+1 landed); barrier; issue
    // ds_reads for slot h+1; MFMA on slot h regs.
    auto body = [&](int h, bf16x8* aCur, bf16x8* bCur, bf16x8* aNxt, bf16x8* bNxt) {
        constexpr int H = KV >> 5;
        if (h + 3 < H) stage(h + 3);
        asm volatile("s_waitcnt lgkmcnt(0)" ::: "memory");
        const int rem = H - 1 - h;
        if (rem >= 3)      asm volatile("s_waitcnt vmcnt(8)" ::: "memory");
        else if (rem == 2) asm volatile("s_waitcnt vmcnt(4)" ::: "memory");
        else if (rem == 1) asm volatile("s_waitcnt vmcnt(0)" ::: "memory");
        __builtin_amdgcn_s_barrier();
        __builtin_amdgcn_sched_barrier(0);
        if (h + 1 < H) lread(aNxt, bNxt, h + 1);
        mm(aCur, bCur);
    };

    constexpr int H = KV >> 5;                        // 32 half-steps for K=1024
    stage(0); stage(1); stage(2);
    asm volatile("s_waitcnt vmcnt(8)" ::: "memory");  // slot 0 landed
    __builtin_amdgcn_s_barrier();
    lread(ra0, rb0, 0);

#pragma unroll
    for (int h = 0; h < H; h += 2) {
        body(h,     ra0, rb0, ra1, rb1);
        body(h + 1, ra1, rb1, ra0, rb0);
    }

#pragma unroll
    for (int m = 0; m < 8; m++) {
        const int gr = m0 + wr + m * 16 + lg * 4;
#pragma unroll
        for (int r = 0; r < 4; r++) {
            float* orow = out + (size_t)(gr + r) * N + n0 + wc + lr;
#pragma unroll
            for (int n = 0; n < 4; n++)
                orow[n * 16] = acc[m][n][r];
        }
    }
}

// ---------------------------------------------------------------------------
// 128x128 GEMM body, BK=32, dbuf LDS, k-slot XOR swizzle (2-way conflicts).
// EPI: 0 = bias->bf16, 1 = bias+gelu->bf16
// ---------------------------------------------------------------------------
template <int EPI>
__device__ __forceinline__ void gemm128(
    const u16* __restrict__ A, const u16* __restrict__ Bt,
    const float* __restrict__ bias,
    u16* __restrict__ outb,
    int M, int N, int K, int bm, int bn)
{
    __shared__ u16 lsA[2][128 * 32];
    __shared__ u16 lsB[2][128 * 32];
    const int tid  = threadIdx.x;
    const int w    = tid >> 6, lane = tid & 63;
    const int lr   = lane & 15, lg = lane >> 4;
    const int m0   = bm * 128, n0 = bn * 128;
    const int wr   = (w >> 1) * 64, wc = (w & 1) * 64;
    f32x4 acc[4][4] = {};

    const int row0 = tid >> 2;
    const int ksw8 = ((lane & 3) ^ ((lane >> 3) & 3)) * 8;
    const u16* a0  = A  + (size_t)(m0 + row0) * K + ksw8;
    const u16* a1  = a0 + (size_t)64 * K;
    const u16* b0p = Bt + (size_t)(n0 + row0) * K + ksw8;
    const u16* b1p = b0p + (size_t)64 * K;
    const int rsw  = (lg ^ ((lr >> 1) & 3)) * 8;

    auto stage = [&](int buf, int ko) {
        char* la = (char*)lsA[buf] + w * 1024;
        char* lb = (char*)lsB[buf] + w * 1024;
        gload16(a0 + ko, la);
        gload16(a1 + ko, la + 4096);
        gload16(b0p + ko, lb);
        gload16(b1p + ko, lb + 4096);
    };
    auto compute = [&](int buf) {
        bf16x8 af[4], bfv[4];
#pragma unroll
        for (int i = 0; i < 4; i++)
            af[i] = *(const bf16x8*)&lsA[buf][(wr + i * 16 + lr) * 32 + rsw];
#pragma unroll
        for (int j = 0; j < 4; j++)
            bfv[j] = *(const bf16x8*)&lsB[buf][(wc + j * 16 + lr) * 32 + rsw];
#pragma unroll
        for (int i = 0; i < 4; i++)
#pragma unroll
            for (int j = 0; j < 4; j++)
                acc[i][j] = mfma16(af[i], bfv[j], acc[i][j]);
    };

    const int nk = K >> 5;
    stage(0, 0);
    __syncthreads();
    int cur = 0;
    for (int kt = 0; kt < nk - 1; ++kt) {
        stage(cur ^ 1, (kt + 1) * 32);
        compute(cur);
        __syncthreads();
        cur ^= 1;
    }
    compute(cur);

#pragma unroll
    for (int j = 0; j < 4; j++) {
        const int gc = n0 + wc + j * 16 + lr;
        const float bv = bias[gc];
#pragma unroll
        for (int i = 0; i < 4; i++) {
            const int grb = m0 + wr + i * 16 + lg * 4;
#pragma unroll
            for (int r = 0; r < 4; r++) {
                float v = acc[i][j][r] + bv;
                if constexpr (EPI == 1) v = 0.5f * v * (1.f + erff(v * 0.70710678118654752f));
                outb[(size_t)(grb + r) * N + gc] = f2b(v);
            }
        }
    }
}

// ---------------------------------------------------------------------------
// 64x128 GEMM body (skinny-N occupancy), 4 waves of 64x32.
// EPI: 0 = bias->bf16, 4 = f32 partial (no bias, split-K)
// ---------------------------------------------------------------------------
template <int EPI>
__device__ __forceinline__ void gemm64(
    const u16* __restrict__ A, int lda, const u16* __restrict__ Bt, int ldb,
    const float* __restrict__ bias,
    float* __restrict__ outf, u16* __restrict__ outb,
    int M, int N, int kc, int bm, int bn)
{
    __shared__ u16 lsA[2][64 * 32];
    __shared__ u16 lsB[2][128 * 32];
    const int tid  = threadIdx.x;
    const int w    = tid >> 6, lane = tid & 63;
    const int lr   = lane & 15, lg = lane >> 4;
    const int m0   = bm * 64, n0 = bn * 128;
    const int wc   = w * 32;
    f32x4 acc[4][2] = {};

    const int row0 = tid >> 2;
    const int ksw8 = ((lane & 3) ^ ((lane >> 3) & 3)) * 8;
    const u16* a0  = A  + (size_t)(m0 + row0) * lda + ksw8;
    const u16* b0p = Bt + (size_t)(n0 + row0) * ldb + ksw8;
    const u16* b1p = b0p + (size_t)64 * ldb;
    const int rsw  = (lg ^ ((lr >> 1) & 3)) * 8;

    auto stage = [&](int buf, int ko) {
        char* la = (char*)lsA[buf] + w * 1024;
        char* lb = (char*)lsB[buf] + w * 1024;
        gload16(a0 + ko, la);
        gload16(b0p + ko, lb);
        gload16(b1p + ko, lb + 4096);
    };
    auto compute = [&](int buf) {
        bf16x8 af[4], bfv[2];
#pragma unroll
        for (int i = 0; i < 4; i++)
            af[i] = *(const bf16x8*)&lsA[buf][(i * 16 + lr) * 32 + rsw];
#pragma unroll
        for (int j = 0; j < 2; j++)
            bfv[j] = *(const bf16x8*)&lsB[buf][(wc + j * 16 + lr) * 32 + rsw];
#pragma unroll
        for (int i = 0; i < 4; i++)
#pragma unroll
            for (int j = 0; j < 2; j++)
                acc[i][j] = mfma16(af[i], bfv[j], acc[i][j]);
    };

    const int nk = kc >> 5;
    stage(0, 0);
    __syncthreads();
    int cur = 0;
    for (int kt = 0; kt < nk - 1; ++kt) {
        stage(cur ^ 1, (kt + 1) * 32);
        compute(cur);
        __syncthreads();
        cur ^= 1;
    }
    compute(cur);

#pragma unroll
    for (int j = 0; j < 2; j++) {
        const int gc = n0 + wc + j * 16 + lr;
        float bv = 0.f;
        if constexpr (EPI == 0) bv = bias[gc];
#pragma unroll
        for (int i = 0; i < 4; i++) {
            const int grb = m0 + i * 16 + lg * 4;
#pragma unroll
            for (int r = 0; r < 4; r++) {
                float v = acc[i][j][r] + bv;
                const size_t o = (size_t)(grb + r) * N + gc;
                if constexpr (EPI == 4) outf[o] = v;
                else                    outb[o] = f2b(v);
            }
        }
    }
}

__global__ __launch_bounds__(256) void gemm128_bias_k(
    const u16* A, const u16* Bt, const float* bias, u16* out, int M, int N, int K, int nbm)
{
    int2 b = swz_bmbn(nbm);
    gemm128<0>(A, Bt, bias, out, M, N, K, b.x, b.y);
}
__global__ __launch_bounds__(256) void gemm64_splitk_k(
    const u16* A, const u16* Bt, float* pbuf, int M, int N, int K, int kc, int nbm)
{
    int2 b = swz_bmbn(nbm);
    const int s = blockIdx.y;
    gemm64<4>(A + (size_t)s * kc, K, Bt + (size_t)s * kc, K, nullptr,
              pbuf + (size_t)s * M * N, nullptr, M, N, kc, b.x, b.y);
}
__global__ __launch_bounds__(256) void gemm128_gelu_k(
    const u16* A, const u16* Bt, const float* bias, u16* out, int M, int N, int K, int nbm)
{
    int2 b = swz_bmbn(nbm);
    gemm128<1>(A, Bt, bias, out, M, N, K, b.x, b.y);
}

// ---------------------------------------------------------------------------
// Split-K reduce + residual + bias, fused with the FOLLOWING LayerNorm.
// ---------------------------------------------------------------------------
__global__ __launch_bounds__(256) void reduce_ln_k(
    const float* __restrict__ pbuf, int S,
    const float* __restrict__ bias,
    float* __restrict__ x,
    const float* __restrict__ g, const float* __restrict__ bln,
    u16* __restrict__ hb)
{
    __shared__ float red[8];
    const int row = blockIdx.x, tid = threadIdx.x;
    const int w = tid >> 6, lane = tid & 63;
    const size_t base = (size_t)row * 256 + tid;
    float4 v = ((const float4*)x)[base];
    for (int s = 0; s < S; ++s) {
        const float4 p = ((const float4*)pbuf)[(size_t)s * 524288 + base];
        v.x += p.x; v.y += p.y; v.z += p.z; v.w += p.w;
    }
    const float4 bb = ((const float4*)bias)[tid];
    v.x += bb.x; v.y += bb.y; v.z += bb.z; v.w += bb.w;
    ((float4*)x)[base] = v;

    float s1 = v.x + v.y + v.z + v.w;
#pragma unroll
    for (int d = 1; d < 64; d <<= 1) s1 += __shfl_xor(s1, d);
    if (lane == 0) red[w] = s1;
    __syncthreads();
    const float mu = (red[0] + red[1] + red[2] + red[3]) * (1.f / 1024.f);
    const float d0 = v.x - mu, d1 = v.y - mu, d2 = v.z - mu, d3 = v.w - mu;
    float s2 = d0 * d0 + d1 * d1 + d2 * d2 + d3 * d3;
#pragma unroll
    for (int d = 1; d < 64; d <<= 1) s2 += __shfl_xor(s2, d);
    if (lane == 0) red[4 + w] = s2;
    __syncthreads();
    const float var = (red[4] + red[5] + red[6] + red[7]) * (1.f / 1024.f);
    const float rs = rsqrtf(var + 1e-5f);
    const float4 gv = ((const float4*)g)[tid];
    const float4 bv = ((const float4*)bln)[tid];
    u32 p0 = (u32)f2b(d0 * rs * gv.x + bv.x) | ((u32)f2b(d1 * rs * gv.y + bv.y) << 16);
    u32 p1 = (u32)f2b(d2 * rs * gv.z + bv.z) | ((u32)f2b(d3 * rs * gv.w + bv.w) << 16);
    ((uint2*)(hb + (size_t)row * 1024))[tid] = make_uint2(p0, p1);
}

// ---------------------------------------------------------------------------
// Flash attention, swapped-operand 32x32x16 structure (m214 port).
// ---------------------------------------------------------------------------
__global__ __launch_bounds__(256) void flash_attn_k(
    const u16* __restrict__ qkv, const u16* __restrict__ vT, u16* __restrict__ out)
{
    constexpr int DS = 3072, T = 2048;
    __shared__ float mrg[2][64][32];
    __shared__ float msh[2][32], lsh[2][32];
    __shared__ u16   sbuf[2][32 * 68];
    const int w = threadIdx.x >> 6, lane = threadIdx.x & 63;
    const int lq = lane & 31, hi = lane >> 5;
    const int hoff = blockIdx.y * 64;
    const int pair = w >> 1, par = w & 1;
    const int qt = (pair == 0) ? blockIdx.x : 63 - blockIdx.x;
    const int q0 = qt * 32;
    const int qg = q0 + lq;

    const u16* qp = qkv + (size_t)qg * DS + hoff;
    const u16* kp = qkv + 1024 + hoff;

    bf16x8 qf[4];
#pragma unroll
    for (int d = 0; d < 4; d++)
        qf[d] = *(const bf16x8*)(qp + d * 16 + hi * 8);

    f32x16 o0 = {}, o1 = {};
    float m_r = -1e30f, l_r = 0.f;

    const int ntiles = (qt >> 1) + 1;
    for (int t = par; t < ntiles; t += 2) {
        const int kv0 = t * 64;
        f32x16 s0 = {}, s1 = {};
        {
            const u16* kb0 = kp + (size_t)(kv0 + lq) * DS + hi * 8;
            const u16* kb1 = kb0 + (size_t)32 * DS;
#pragma unroll
            for (int d = 0; d < 4; d++) {
                s0 = mfma32(*(const bf16x8*)(kb0 + d * 16), qf[d], s0);
                s1 = mfma32(*(const bf16x8*)(kb1 + d * 16), qf[d], s1);
            }
        }
        float p[32];
        float mx = -1e30f;
#pragma unroll
        for (int r = 0; r < 16; r++) {
            const int kvl = (r & 3) + 8 * (r >> 2) + 4 * hi;
            float v0 = (kv0 + kvl      <= qg) ? s0[r] * 0.125f : -1e30f;
            float v1 = (kv0 + 32 + kvl <= qg) ? s1[r] * 0.125f : -1e30f;
            p[r] = v0; p[16 + r] = v1;
            mx = fmaxf(mx, fmaxf(v0, v1));
        }
        mx = fmaxf(mx, __shfl_xor(mx, 32));
        const float mn = fmaxf(m_r, mx);
        const float alpha = __expf(m_r - mn);
        m_r = mn;
        float ls = 0.f;
#pragma unroll
        for (int i = 0; i < 32; i++) { p[i] = __expf(p[i] - mn); ls += p[i]; }
        ls += __shfl_xor(ls, 32);
        l_r = l_r * alpha + ls;
#pragma unroll
        for (int r = 0; r < 16; r++) { o0[r] *= alpha; o1[r] *= alpha; }
#pragma unroll
        for (int sub = 0; sub < 2; sub++) {
            u32 pw[8], x[8];
#pragma unroll
            for (int i = 0; i < 8; i++)
                pw[i] = (u32)f2b(p[sub * 16 + 2 * i]) | ((u32)f2b(p[sub * 16 + 2 * i + 1]) << 16);
#pragma unroll
            for (int i = 0; i < 8; i++) x[i] = __shfl_xor(pw[i], 32);
            u32 b0[4], b1[4];
            b0[0] = hi ? x[2]  : pw[0];  b0[1] = hi ? x[3]  : pw[1];
            b0[2] = hi ? pw[2] : x[0];   b0[3] = hi ? pw[3] : x[1];
            b1[0] = hi ? x[6]  : pw[4];  b1[1] = hi ? x[7]  : pw[5];
            b1[2] = hi ? pw[6] : x[4];   b1[3] = hi ? pw[7] : x[5];
            bf16x8 B0 = __builtin_bit_cast(bf16x8, *(const uint4*)b0);
            bf16x8 B1 = __builtin_bit_cast(bf16x8, *(const uint4*)b1);
            const u16* vb = vT + (size_t)(hoff + lq) * T + kv0 + sub * 32 + hi * 8;
            o0 = mfma32(*(const bf16x8*)vb, B0, o0);
            o0 = mfma32(*(const bf16x8*)(vb + 16), B1, o0);
            const u16* vb1 = vb + (size_t)32 * T;
            o1 = mfma32(*(const bf16x8*)vb1, B0, o1);
            o1 = mfma32(*(const bf16x8*)(vb1 + 16), B1, o1);
        }
    }

    __syncthreads();
    if (par == 0) {
#pragma unroll
        for (int r = 0; r < 16; r++) {
            const int d = (r & 3) + 8 * (r >> 2) + 4 * hi;
            mrg[pair][d][lq]      = o0[r];
            mrg[pair][d + 32][lq] = o1[r];
        }
        if (hi == 0) { msh[pair][lq] = m_r; lsh[pair][lq] = l_r; }
    }
    __syncthreads();
    if (par == 1) {
        const float m0v = msh[pair][lq], l0v = lsh[pair][lq];
        const float M = fmaxf(m0v, m_r);
        const float f0 = __expf(m0v - M), f1 = __expf(m_r - M);
        const float linv = 1.f / (l0v * f0 + l_r * f1);
        u32* sb = (u32*)sbuf[pair];
#pragma unroll
        for (int r = 0; r < 16; r += 2) {
            const int d = (r & 3) + 8 * (r >> 2) + 4 * hi;
            float va = (mrg[pair][d][lq] * f0 + o0[r] * f1) * linv;
            float vb = (mrg[pair][d + 1][lq] * f0 + o0[r + 1] * f1) * linv;
            sb[lq * 34 + (d >> 1)] = (u32)f2b(va) | ((u32)f2b(vb) << 16);
            float vc = (mrg[pair][d + 32][lq] * f0 + o1[r] * f1) * linv;
            float vd = (mrg[pair][d + 33][lq] * f0 + o1[r + 1] * f1) * linv;
            sb[lq * 34 + ((d + 32) >> 1)] = (u32)f2b(vc) | ((u32)f2b(vd) << 16);
        }
#pragma unroll
        for (int ps = 0; ps < 8; ps++) {
            const int row = ps * 4 + (lane >> 4);
            const uint2 v = *(const uint2*)&sbuf[pair][row * 68 + (lane & 15) * 4];
            *(uint2*)(out + (size_t)(q0 + row) * 1024 + hoff + (lane & 15) * 4) = v;
        }
    }
}

// ---------------------------------------------------------------------------
__global__ __launch_bounds__(256) void transpose_cvt_k(
    const float* __restrict__ src, u16* __restrict__ dst, int K, int N,
    long long srcLS, long long dstLS)
{
    __shared__ float tile[32][33];
    src += (size_t)blockIdx.z * srcLS;
    dst += (size_t)blockIdx.z * dstLS;
    const int n0 = blockIdx.x * 32, k0 = blockIdx.y * 32;
    const int tx = threadIdx.x & 31, ty = threadIdx.x >> 5;
#pragma unroll
    for (int r = 0; r < 32; r += 8)
        tile[ty + r][tx] = src[(size_t)(k0 + ty + r) * N + n0 + tx];
    __syncthreads();
#pragma unroll
    for (int r = 0; r < 32; r += 8)
        dst[(size_t)(n0 + ty + r) * K + k0 + tx] = f2b(tile[tx][ty + r]);
}

__global__ __launch_bounds__(256) void transpose_u16_k(
    const u16* __restrict__ src, u16* __restrict__ dst, int R, int C, int srcStride)
{
    __shared__ u16 tile[32][33];
    const int c0 = blockIdx.x * 32, r0 = blockIdx.y * 32;
    const int tx = threadIdx.x & 31, ty = threadIdx.x >> 5;
#pragma unroll
    for (int r = 0; r < 32; r += 8)
        tile[ty + r][tx] = src[(size_t)(r0 + ty + r) * srcStride + c0 + tx];
    __syncthreads();
#pragma unroll
    for (int r = 0; r < 32; r += 8)
        dst[(size_t)(c0 + ty + r) * R + r0 + tx] = tile[tx][ty + r];
}

__global__ __launch_bounds__(256) void concat_bias_k(
    const float* __restrict__ bq, const float* __restrict__ bk,
    const float* __restrict__ bv, float* __restrict__ bcat)
{
    const int l = blockIdx.y;
    const int j = blockIdx.x * 256 + threadIdx.x;
    float v;
    if (j < 1024)      v = bq[l * 1024 + j];
    else if (j < 2048) v = bk[l * 1024 + j - 1024];
    else               v = bv[l * 1024 + j - 2048];
    bcat[l * 3072 + j] = v;
}

__global__ __launch_bounds__(256) void embed_pos_k(
    const int* __restrict__ idx, const float* __restrict__ emb, float* __restrict__ x)
{
    const int t = blockIdx.x, tid = threadIdx.x;
    const int tok = idx[t];
    float4 e = ((const float4*)(emb + (size_t)tok * 1024))[tid];
    const int d0 = tid * 4;
    const float c = -0.0089944730195080f;
    const float a0 = (float)t * expf((float)d0 * c);
    const float a1 = (float)t * expf((float)(d0 + 2) * c);
    e.x += sinf(a0); e.y += cosf(a0); e.z += sinf(a1); e.w += cosf(a1);
    ((float4*)(x + (size_t)t * 1024))[tid] = e;
}

__global__ __launch_bounds__(256) void layernorm_k(
    const float* __restrict__ x, const float* __restrict__ g,
    const float* __restrict__ b, u16* __restrict__ out)
{
    __shared__ float red[8];
    const int row = blockIdx.x, tid = threadIdx.x;
    const int w = tid >> 6, lane = tid & 63;
    const float4 v = ((const float4*)(x + (size_t)row * 1024))[tid];
    float s = v.x + v.y + v.z + v.w;
#pragma unroll
    for (int d = 1; d < 64; d <<= 1) s += __shfl_xor(s, d);
    if (lane == 0) red[w] = s;
    __syncthreads();
    const float mu = (red[0] + red[1] + red[2] + red[3]) * (1.f / 1024.f);
    const float d0 = v.x - mu, d1 = v.y - mu, d2 = v.z - mu, d3 = v.w - mu;
    float s2 = d0 * d0 + d1 * d1 + d2 * d2 + d3 * d3;
#pragma unroll
    for (int d = 1; d < 64; d <<= 1) s2 += __shfl_xor(s2, d);
    if (lane == 0) red[4 + w] = s2;
    __syncthreads();
    const float var = (red[4] + red[5] + red[6] + red[7]) * (1.f / 1024.f);
    const float rs = rsqrtf(var + 1e-5f);
    const float4 gv = ((const float4*)g)[tid];
    const float4 bv = ((const float4*)b)[tid];
    u32 p0 = (u32)f2b(d0 * rs * gv.x + bv.x) | ((u32)f2b(d1 * rs * gv.y + bv.y) << 16);
    u32 p1 = (u32)f2b(d2 * rs * gv.z + bv.z) | ((u32)f2b(d3 * rs * gv.w + bv.w) << 16);
    ((uint2*)(out + (size_t)row * 1024))[tid] = make_uint2(p0, p1);
}

// ---------------------------------------------------------------------------
extern "C" void kernel_launch(void* const* d_in, const int* in_sizes, int n_in,
                              void* d_out, int out_size, void* d_ws, size_t ws_size,
                              hipStream_t stream)
{
    const int*   idx   = (const int*)  d_in[0];
    const float* embed = (const float*)d_in[1];
    const float* Wq    = (const float*)d_in[2];
    const float* Wk    = (const float*)d_in[3];
    const float* Wv    = (const float*)d_in[4];
    const float* Wo    = (const float*)d_in[5];
    const float* bq    = (const float*)d_in[6];
    const float* bk    = (const float*)d_in[7];
    const float* bv    = (const float*)d_in[8];
    const float* bo    = (const float*)d_in[9];
    const float* ln1g  = (const float*)d_in[10];
    const float* ln1b  = (const float*)d_in[11];
    const float* ln2g  = (const float*)d_in[12];
    const float* ln2b  = (const float*)d_in[13];
    const float* w1    = (const float*)d_in[14];
    const float* b1    = (const float*)d_in[15];
    const float* w2    = (const float*)d_in[16];
    const float* b2    = (const float*)d_in[17];
    const float* lnfg  = (const float*)d_in[18];
    const float* lnfb  = (const float*)d_in[19];
    const float* headw = (const float*)d_in[20];

    char* ws = (char*)d_ws;
    auto alloc = [&](size_t bytes) {
        char* p = ws;
        ws += (bytes + 255) & ~(size_t)255;
        return p;
    };
    u16*   qkvT = (u16*)alloc((size_t)4 * 3072 * 1024 * 2);
    u16*   WoT  = (u16*)alloc((size_t)4 * 1024 * 1024 * 2);
    u16*   w1T  = (u16*)alloc((size_t)4 * 1024 * 4096 * 2);
    u16*   w2T  = (u16*)alloc((size_t)4 * 1024 * 4096 * 2);
    u16*   hT   = (u16*)alloc((size_t)32000 * 1024 * 2);
    float* bcat = (float*)alloc((size_t)4 * 3072 * 4);
    float* x    = (float*)alloc((size_t)2048 * 1024 * 4);
    u16*   hb   = (u16*)alloc((size_t)2048 * 1024 * 2);
    u16*   qkvb = (u16*)alloc((size_t)2048 * 3072 * 2);
    u16*   vTb  = (u16*)alloc((size_t)2048 * 1024 * 2);
    u16*   ab   = (u16*)alloc((size_t)2048 * 1024 * 2);
    u16*   ff   = (u16*)alloc((size_t)2048 * 4096 * 2);
    float* pbuf = (float*)d_out;   // split-K partials; head GEMM overwrites at the end

    transpose_cvt_k<<<dim3(32, 32, 4),  256, 0, stream>>>(Wq, qkvT,            1024, 1024, 1048576, 3145728);
    transpose_cvt_k<<<dim3(32, 32, 4),  256, 0, stream>>>(Wk, qkvT + 1048576,  1024, 1024, 1048576, 3145728);
    transpose_cvt_k<<<dim3(32, 32, 4),  256, 0, stream>>>(Wv, qkvT + 2097152,  1024, 1024, 1048576, 3145728);
    transpose_cvt_k<<<dim3(32, 32, 4),  256, 0, stream>>>(Wo, WoT,             1024, 1024, 1048576, 1048576);
    transpose_cvt_k<<<dim3(128, 32, 4), 256, 0, stream>>>(w1, w1T,             1024, 4096, 4194304, 4194304);
    transpose_cvt_k<<<dim3(32, 128, 4), 256, 0, stream>>>(w2, w2T,             4096, 1024, 4194304, 4194304);
    transpose_cvt_k<<<dim3(1000, 32, 1), 256, 0, stream>>>(headw, hT,          1024, 32000, 0, 0);
    concat_bias_k<<<dim3(12, 4), 256, 0, stream>>>(bq, bk, bv, bcat);

    embed_pos_k<<<dim3(2048), 256, 0, stream>>>(idx, embed, x);
    layernorm_k<<<dim3(2048), 256, 0, stream>>>(x, ln1g, ln1b, hb);

    for (int l = 0; l < 4; ++l) {
        gemm128_bias_k<<<dim3(384), 256, 0, stream>>>(hb, qkvT + (size_t)l * 3145728,
                                                      bcat + l * 3072, qkvb, 2048, 3072, 1024, 16);
        transpose_u16_k<<<dim3(32, 64), 256, 0, stream>>>(qkvb + 2048, vTb, 2048, 1024, 3072);
        flash_attn_k<<<dim3(32, 16), 256, 0, stream>>>(qkvb, vTb, ab);
        gemm64_splitk_k<<<dim3(256, 2), 256, 0, stream>>>(ab, WoT + (size_t)l * 1048576,
                                                          pbuf, 2048, 1024, 1024, 512, 32);
        reduce_ln_k<<<dim3(2048), 256, 0, stream>>>(pbuf, 2, bo + l * 1024, x,
                                                    ln2g + l * 1024, ln2b + l * 1024, hb);
        gemm128_gelu_k<<<dim3(512), 256, 0, stream>>>(hb, w1T + (size_t)l * 4194304,
                                                      b1 + l * 4096, ff, 2048, 4096, 1024, 16);
        gemm64_splitk_k<<<dim3(256, 4), 256, 0, stream>>>(ff, w2T + (size_t)l * 4194304,
                                                          pbuf, 2048, 1024, 4096, 1024, 32);
        const float* ng = (l < 3) ? (ln1g + (l + 1) * 1024) : lnfg;
        const float* nb = (l < 3) ? (ln1b + (l + 1) * 1024) : lnfb;
        reduce_ln_k<<<dim3(2048), 256, 0, stream>>>(pbuf, 4, b2 + l * 1024, x, ng, nb, hb);
    }
    gemm256_head_k<1024><<<dim3(1000), 512, 0, stream>>>(hb, hT, (float*)d_out, 2048, 32000);
}

// Round 7
// 983.393 us; speedup vs baseline: 1.7579x; 1.0568x over previous
//
#include <hip/hip_runtime.h>
#include <cstdint>

using u16 = unsigned short;
using u32 = unsigned int;
typedef __bf16  bf16x8 __attribute__((ext_vector_type(8)));
typedef float   f32x4  __attribute__((ext_vector_type(4)));
typedef float   f32x16 __attribute__((ext_vector_type(16)));

__device__ __forceinline__ u16 f2b(float x) {
    u32 u = __builtin_bit_cast(u32, x);
    u = (u + 0x7fffu + ((u >> 16) & 1u)) >> 16;
    return (u16)u;
}

__device__ __forceinline__ f32x4 mfma16(bf16x8 a, bf16x8 b, f32x4 c) {
    return __builtin_amdgcn_mfma_f32_16x16x32_bf16(a, b, c, 0, 0, 0);
}
__device__ __forceinline__ f32x16 mfma32(bf16x8 a, bf16x8 b, f32x16 c) {
    return __builtin_amdgcn_mfma_f32_32x32x16_bf16(a, b, c, 0, 0, 0);
}

__device__ __forceinline__ void gload16(const void* g, void* lds) {
    auto gp = (__attribute__((address_space(1))) void*)(uintptr_t)g;
    auto lp = (__attribute__((address_space(3))) void*)(uintptr_t)lds;
    __builtin_amdgcn_global_load_lds(gp, lp, 16, 0, 0);
}

// bijective XCD-aware swizzle (m204); bm fastest so co-resident blocks share B panels
__device__ __forceinline__ int2 swz_bmbn(int nbm) {
    const int nwg = gridDim.x, orig = blockIdx.x;
    const int q = nwg >> 3, r = nwg & 7;
    const int xcd = orig & 7, lin = orig >> 3;
    const int id = (xcd < r ? xcd * (q + 1) : r * (q + 1) + (xcd - r) * q) + lin;
    return make_int2(id % nbm, id / nbm);
}

// ---------------------------------------------------------------------------
// Deep-pipelined GEMM template. BM=BN tile (256: 8 waves of 128x64, 128 KB LDS,
// 1 blk/CU; 128: 4 waves of 64x64, 64 KB LDS, 2 blk/CU). Ring of 4 half-slots
// (32 k-elems each), 3-ahead vmem staging with counted vmcnt (8/4/0), one
// barrier per half-slot, one-slot-ahead register pipeline with the next-slot
// ds_reads interleaved into the MFMA cluster (4 groups). lgkmcnt(0) stays
// BEFORE the barrier: it guarantees all waves' reads of slot h-1 are drained
// before any wave's stage(h+3) can overwrite it.
// EPI: 0 bias->bf16, 1 bias+gelu->bf16, 3 plain f32, 4 f32 split-K partial.
// splitk: s = blockIdx.y; A/Bt advance s*skA/skB elems, outf by s*sOut.
// ---------------------------------------------------------------------------
template <int BM, int KC, int EPI>
__global__ __launch_bounds__(BM == 256 ? 512 : 256, 2) void gemm_deep_k(
    const u16* __restrict__ A, int lda, const u16* __restrict__ Bt, int ldb,
    const float* __restrict__ bias, float* __restrict__ outf,
    u16* __restrict__ outb, int N, int nbm, int sk, long long sOut)
{
    constexpr int NW    = (BM == 256) ? 8 : 4;
    constexpr int WCOLS = (BM == 256) ? 4 : 2;
    constexpr int MF    = BM / 32;            // 8 or 4 m-fragments per wave
    constexpr int NF    = 4;
    constexpr int SLOT  = BM * 32;            // elems per half-slot per matrix
    constexpr int HALF  = (BM / 2) * 32;
    constexpr int H     = KC >> 5;
    constexpr int RPG   = (MF + NF) / 4;      // reads per interleave group
    constexpr int MPG   = (MF * NF) / 4;      // mfma per interleave group

    __shared__ __align__(16) u16 lsA[4][SLOT];
    __shared__ __align__(16) u16 lsB[4][SLOT];

    const int s = blockIdx.y;
    A  += (size_t)s * sk;
    Bt += (size_t)s * sk;
    if (EPI == 4) outf += (size_t)s * sOut;

    const int2 bb = swz_bmbn(nbm);
    const int m0 = bb.x * BM, n0 = bb.y * BM;
    const int tid = threadIdx.x;
    const int w = tid >> 6, lane = tid & 63;
    const int wr = (w / WCOLS) * (MF * 16), wc = (w % WCOLS) * 64;
    const int lr = lane & 15, lg = lane >> 4;
    const int rsw = (lg ^ ((lr >> 1) & 3)) * 8;

    const int trow = tid >> 2;                // 0..BM/2-1
    const int ksw8 = ((tid & 3) ^ ((tid >> 3) & 3)) * 8;
    const u16* aA = A  + (size_t)(m0 + trow) * lda + ksw8;
    const u16* aB = Bt + (size_t)(n0 + trow) * ldb + ksw8;
    u16* dA = &lsA[0][0] + trow * 32 + (tid & 3) * 8;
    u16* dB = &lsB[0][0] + trow * 32 + (tid & 3) * 8;

    f32x4 acc[MF][NF] = {};

    auto stage = [&](int h) {
        const int sl = h & 3;
        const int koff = h * 32;
        gload16(aA + koff,                          dA + sl * SLOT);
        gload16(aA + koff + (size_t)(BM / 2) * lda, dA + sl * SLOT + HALF);
        gload16(aB + koff,                          dB + sl * SLOT);
        gload16(aB + koff + (size_t)(BM / 2) * ldb, dB + sl * SLOT + HALF);
    };

    bf16x8 ra0[MF], rb0[NF], ra1[MF], rb1[NF];  // two named reg sets (rule #20)
    auto lreadAll = [&](bf16x8* af, bf16x8* bf, int h) {
        const int sl = h & 3;
#pragma unroll
        for (int m = 0; m < MF; m++)
            af[m] = *(const bf16x8*)&lsA[sl][(wr + m * 16 + lr) * 32 + rsw];
#pragma unroll
        for (int n = 0; n < NF; n++)
            bf[n] = *(const bf16x8*)&lsB[sl][(wc + n * 16 + lr) * 32 + rsw];
    };

    auto body = [&](int h, bf16x8* aC, bf16x8* bC, bf16x8* aN, bf16x8* bN) {
        if (h + 3 < H) stage(h + 3);
        __builtin_amdgcn_sched_barrier(0);
        asm volatile("s_waitcnt lgkmcnt(0)" ::: "memory");
        const int rem = H - 1 - h;
        if (rem >= 3)      asm volatile("s_waitcnt vmcnt(8)" ::: "memory");
        else if (rem == 2) asm volatile("s_waitcnt vmcnt(4)" ::: "memory");
        else if (rem == 1) asm volatile("s_waitcnt vmcnt(0)" ::: "memory");
        __builtin_amdgcn_s_barrier();
        __builtin_amdgcn_sched_barrier(0);
        const int sl1 = (h + 1) & 3;
        const bool doRead = (h + 1 < H);
#pragma unroll
        for (int g = 0; g < 4; ++g) {
            if (doRead) {
#pragma unroll
                for (int t = g * RPG; t < (g + 1) * RPG; ++t) {
                    if (t < MF) aN[t]      = *(const bf16x8*)&lsA[sl1][(wr + t * 16 + lr) * 32 + rsw];
                    else        bN[t - MF] = *(const bf16x8*)&lsB[sl1][(wc + (t - MF) * 16 + lr) * 32 + rsw];
                }
            }
            __builtin_amdgcn_sched_barrier(0);
            __builtin_amdgcn_s_setprio(1);
#pragma unroll
            for (int i = g * MPG; i < (g + 1) * MPG; ++i)
                acc[i / NF][i % NF] = mfma16(aC[i / NF], bC[i % NF], acc[i / NF][i % NF]);
            __builtin_amdgcn_s_setprio(0);
            __builtin_amdgcn_sched_barrier(0);
        }
    };

    stage(0); stage(1); stage(2);
    asm volatile("s_waitcnt vmcnt(8)" ::: "memory");  // slot 0 landed
    __builtin_amdgcn_s_barrier();
    lreadAll(ra0, rb0, 0);

#pragma unroll
    for (int h = 0; h < H; h += 2) {
        body(h,     ra0, rb0, ra1, rb1);
        body(h + 1, ra1, rb1, ra0, rb0);
    }

#pragma unroll
    for (int n = 0; n < NF; n++) {
        const int gc = n0 + wc + n * 16 + lr;
        float bv = 0.f;
        if constexpr (EPI == 0 || EPI == 1) bv = bias[gc];
#pragma unroll
        for (int m = 0; m < MF; m++) {
            const int grb = m0 + wr + m * 16 + lg * 4;
#pragma unroll
            for (int r = 0; r < 4; r++) {
                float v = acc[m][n][r] + bv;
                if constexpr (EPI == 1) v = 0.5f * v * (1.f + erff(v * 0.70710678118654752f));
                const size_t o = (size_t)(grb + r) * N + gc;
                if constexpr (EPI == 3 || EPI == 4) outf[o] = v;
                else                                outb[o] = f2b(v);
            }
        }
    }
}

// ---------------------------------------------------------------------------
// Split-K reduce + residual + bias, fused with the FOLLOWING LayerNorm.
// ---------------------------------------------------------------------------
__global__ __launch_bounds__(256) void reduce_ln_k(
    const float* __restrict__ pbuf, int S,
    const float* __restrict__ bias,
    float* __restrict__ x,
    const float* __restrict__ g, const float* __restrict__ bln,
    u16* __restrict__ hb)
{
    __shared__ float red[8];
    const int row = blockIdx.x, tid = threadIdx.x;
    const int w = tid >> 6, lane = tid & 63;
    const size_t base = (size_t)row * 256 + tid;
    float4 v = ((const float4*)x)[base];
    for (int s = 0; s < S; ++s) {
        const float4 p = ((const float4*)pbuf)[(size_t)s * 524288 + base];
        v.x += p.x; v.y += p.y; v.z += p.z; v.w += p.w;
    }
    const float4 bb = ((const float4*)bias)[tid];
    v.x += bb.x; v.y += bb.y; v.z += bb.z; v.w += bb.w;
    ((float4*)x)[base] = v;

    float s1 = v.x + v.y + v.z + v.w;
#pragma unroll
    for (int d = 1; d < 64; d <<= 1) s1 += __shfl_xor(s1, d);
    if (lane == 0) red[w] = s1;
    __syncthreads();
    const float mu = (red[0] + red[1] + red[2] + red[3]) * (1.f / 1024.f);
    const float d0 = v.x - mu, d1 = v.y - mu, d2 = v.z - mu, d3 = v.w - mu;
    float s2 = d0 * d0 + d1 * d1 + d2 * d2 + d3 * d3;
#pragma unroll
    for (int d = 1; d < 64; d <<= 1) s2 += __shfl_xor(s2, d);
    if (lane == 0) red[4 + w] = s2;
    __syncthreads();
    const float var = (red[4] + red[5] + red[6] + red[7]) * (1.f / 1024.f);
    const float rs = rsqrtf(var + 1e-5f);
    const float4 gv = ((const float4*)g)[tid];
    const float4 bv = ((const float4*)bln)[tid];
    u32 p0 = (u32)f2b(d0 * rs * gv.x + bv.x) | ((u32)f2b(d1 * rs * gv.y + bv.y) << 16);
    u32 p1 = (u32)f2b(d2 * rs * gv.z + bv.z) | ((u32)f2b(d3 * rs * gv.w + bv.w) << 16);
    ((uint2*)(hb + (size_t)row * 1024))[tid] = make_uint2(p0, p1);
}

// ---------------------------------------------------------------------------
// Flash attention, swapped-operand 32x32x16 structure (m214 port).
// ---------------------------------------------------------------------------
__global__ __launch_bounds__(256) void flash_attn_k(
    const u16* __restrict__ qkv, const u16* __restrict__ vT, u16* __restrict__ out)
{
    constexpr int DS = 3072, T = 2048;
    __shared__ float mrg[2][64][32];
    __shared__ float msh[2][32], lsh[2][32];
    __shared__ u16   sbuf[2][32 * 68];
    const int w = threadIdx.x >> 6, lane = threadIdx.x & 63;
    const int lq = lane & 31, hi = lane >> 5;
    const int hoff = blockIdx.y * 64;
    const int pair = w >> 1, par = w & 1;
    const int qt = (pair == 0) ? blockIdx.x : 63 - blockIdx.x;
    const int q0 = qt * 32;
    const int qg = q0 + lq;

    const u16* qp = qkv + (size_t)qg * DS + hoff;
    const u16* kp = qkv + 1024 + hoff;

    bf16x8 qf[4];
#pragma unroll
    for (int d = 0; d < 4; d++)
        qf[d] = *(const bf16x8*)(qp + d * 16 + hi * 8);

    f32x16 o0 = {}, o1 = {};
    float m_r = -1e30f, l_r = 0.f;

    const int ntiles = (qt >> 1) + 1;
    for (int t = par; t < ntiles; t += 2) {
        const int kv0 = t * 64;
        f32x16 s0 = {}, s1 = {};
        {
            const u16* kb0 = kp + (size_t)(kv0 + lq) * DS + hi * 8;
            const u16* kb1 = kb0 + (size_t)32 * DS;
#pragma unroll
            for (int d = 0; d < 4; d++) {
                s0 = mfma32(*(const bf16x8*)(kb0 + d * 16), qf[d], s0);
                s1 = mfma32(*(const bf16x8*)(kb1 + d * 16), qf[d], s1);
            }
        }
        float p[32];
        float mx = -1e30f;
#pragma unroll
        for (int r = 0; r < 16; r++) {
            const int kvl = (r & 3) + 8 * (r >> 2) + 4 * hi;
            float v0 = (kv0 + kvl      <= qg) ? s0[r] * 0.125f : -1e30f;
            float v1 = (kv0 + 32 + kvl <= qg) ? s1[r] * 0.125f : -1e30f;
            p[r] = v0; p[16 + r] = v1;
            mx = fmaxf(mx, fmaxf(v0, v1));
        }
        mx = fmaxf(mx, __shfl_xor(mx, 32));
        const float mn = fmaxf(m_r, mx);
        const float alpha = __expf(m_r - mn);
        m_r = mn;
        float ls = 0.f;
#pragma unroll
        for (int i = 0; i < 32; i++) { p[i] = __expf(p[i] - mn); ls += p[i]; }
        ls += __shfl_xor(ls, 32);
        l_r = l_r * alpha + ls;
#pragma unroll
        for (int r = 0; r < 16; r++) { o0[r] *= alpha; o1[r] *= alpha; }
#pragma unroll
        for (int sub = 0; sub < 2; sub++) {
            u32 pw[8], x[8];
#pragma unroll
            for (int i = 0; i < 8; i++)
                pw[i] = (u32)f2b(p[sub * 16 + 2 * i]) | ((u32)f2b(p[sub * 16 + 2 * i + 1]) << 16);
#pragma unroll
            for (int i = 0; i < 8; i++) x[i] = __shfl_xor(pw[i], 32);
            u32 b0[4], b1[4];
            b0[0] = hi ? x[2]  : pw[0];  b0[1] = hi ? x[3]  : pw[1];
            b0[2] = hi ? pw[2] : x[0];   b0[3] = hi ? pw[3] : x[1];
            b1[0] = hi ? x[6]  : pw[4];  b1[1] = hi ? x[7]  : pw[5];
            b1[2] = hi ? pw[6] : x[4];   b1[3] = hi ? pw[7] : x[5];
            bf16x8 B0 = __builtin_bit_cast(bf16x8, *(const uint4*)b0);
            bf16x8 B1 = __builtin_bit_cast(bf16x8, *(const uint4*)b1);
            const u16* vb = vT + (size_t)(hoff + lq) * T + kv0 + sub * 32 + hi * 8;
            o0 = mfma32(*(const bf16x8*)vb, B0, o0);
            o0 = mfma32(*(const bf16x8*)(vb + 16), B1, o0);
            const u16* vb1 = vb + (size_t)32 * T;
            o1 = mfma32(*(const bf16x8*)vb1, B0, o1);
            o1 = mfma32(*(const bf16x8*)(vb1 + 16), B1, o1);
        }
    }

    __syncthreads();
    if (par == 0) {
#pragma unroll
        for (int r = 0; r < 16; r++) {
            const int d = (r & 3) + 8 * (r >> 2) + 4 * hi;
            mrg[pair][d][lq]      = o0[r];
            mrg[pair][d + 32][lq] = o1[r];
        }
        if (hi == 0) { msh[pair][lq] = m_r; lsh[pair][lq] = l_r; }
    }
    __syncthreads();
    if (par == 1) {
        const float m0v = msh[pair][lq], l0v = lsh[pair][lq];
        const float M = fmaxf(m0v, m_r);
        const float f0 = __expf(m0v - M), f1 = __expf(m_r - M);
        const float linv = 1.f / (l0v * f0 + l_r * f1);
        u32* sb = (u32*)sbuf[pair];
#pragma unroll
        for (int r = 0; r < 16; r += 2) {
            const int d = (r & 3) + 8 * (r >> 2) + 4 * hi;
            float va = (mrg[pair][d][lq] * f0 + o0[r] * f1) * linv;
            float vb = (mrg[pair][d + 1][lq] * f0 + o0[r + 1] * f1) * linv;
            sb[lq * 34 + (d >> 1)] = (u32)f2b(va) | ((u32)f2b(vb) << 16);
            float vc = (mrg[pair][d + 32][lq] * f0 + o1[r] * f1) * linv;
            float vd = (mrg[pair][d + 33][lq] * f0 + o1[r + 1] * f1) * linv;
            sb[lq * 34 + ((d + 32) >> 1)] = (u32)f2b(vc) | ((u32)f2b(vd) << 16);
        }
#pragma unroll
        for (int ps = 0; ps < 8; ps++) {
            const int row = ps * 4 + (lane >> 4);
            const uint2 v = *(const uint2*)&sbuf[pair][row * 68 + (lane & 15) * 4];
            *(uint2*)(out + (size_t)(q0 + row) * 1024 + hoff + (lane & 15) * 4) = v;
        }
    }
}

// ---------------------------------------------------------------------------
__global__ __launch_bounds__(256) void transpose_cvt_k(
    const float* __restrict__ src, u16* __restrict__ dst, int K, int N,
    long long srcLS, long long dstLS)
{
    __shared__ float tile[32][33];
    src += (size_t)blockIdx.z * srcLS;
    dst += (size_t)blockIdx.z * dstLS;
    const int n0 = blockIdx.x * 32, k0 = blockIdx.y * 32;
    const int tx = threadIdx.x & 31, ty = threadIdx.x >> 5;
#pragma unroll
    for (int r = 0; r < 32; r += 8)
        tile[ty + r][tx] = src[(size_t)(k0 + ty + r) * N + n0 + tx];
    __syncthreads();
#pragma unroll
    for (int r = 0; r < 32; r += 8)
        dst[(size_t)(n0 + ty + r) * K + k0 + tx] = f2b(tile[tx][ty + r]);
}

__global__ __launch_bounds__(256) void transpose_u16_k(
    const u16* __restrict__ src, u16* __restrict__ dst, int R, int C, int srcStride)
{
    __shared__ u16 tile[32][33];
    const int c0 = blockIdx.x * 32, r0 = blockIdx.y * 32;
    const int tx = threadIdx.x & 31, ty = threadIdx.x >> 5;
#pragma unroll
    for (int r = 0; r < 32; r += 8)
        tile[ty + r][tx] = src[(size_t)(r0 + ty + r) * srcStride + c0 + tx];
    __syncthreads();
#pragma unroll
    for (int r = 0; r < 32; r += 8)
        dst[(size_t)(c0 + ty + r) * R + r0 + tx] = tile[tx][ty + r];
}

__global__ __launch_bounds__(256) void concat_bias_k(
    const float* __restrict__ bq, const float* __restrict__ bk,
    const float* __restrict__ bv, float* __restrict__ bcat)
{
    const int l = blockIdx.y;
    const int j = blockIdx.x * 256 + threadIdx.x;
    float v;
    if (j < 1024)      v = bq[l * 1024 + j];
    else if (j < 2048) v = bk[l * 1024 + j - 1024];
    else               v = bv[l * 1024 + j - 2048];
    bcat[l * 3072 + j] = v;
}

__global__ __launch_bounds__(256) void embed_pos_k(
    const int* __restrict__ idx, const float* __restrict__ emb, float* __restrict__ x)
{
    const int t = blockIdx.x, tid = threadIdx.x;
    const int tok = idx[t];
    float4 e = ((const float4*)(emb + (size_t)tok * 1024))[tid];
    const int d0 = tid * 4;
    const float c = -0.0089944730195080f;
    const float a0 = (float)t * expf((float)d0 * c);
    const float a1 = (float)t * expf((float)(d0 + 2) * c);
    e.x += sinf(a0); e.y += cosf(a0); e.z += sinf(a1); e.w += cosf(a1);
    ((float4*)(x + (size_t)t * 1024))[tid] = e;
}

__global__ __launch_bounds__(256) void layernorm_k(
    const float* __restrict__ x, const float* __restrict__ g,
    const float* __restrict__ b, u16* __restrict__ out)
{
    __shared__ float red[8];
    const int row = blockIdx.x, tid = threadIdx.x;
    const int w = tid >> 6, lane = tid & 63;
    const float4 v = ((const float4*)(x + (size_t)row * 1024))[tid];
    float s = v.x + v.y + v.z + v.w;
#pragma unroll
    for (int d = 1; d < 64; d <<= 1) s += __shfl_xor(s, d);
    if (lane == 0) red[w] = s;
    __syncthreads();
    const float mu = (red[0] + red[1] + red[2] + red[3]) * (1.f / 1024.f);
    const float d0 = v.x - mu, d1 = v.y - mu, d2 = v.z - mu, d3 = v.w - mu;
    float s2 = d0 * d0 + d1 * d1 + d2 * d2 + d3 * d3;
#pragma unroll
    for (int d = 1; d < 64; d <<= 1) s2 += __shfl_xor(s2, d);
    if (lane == 0) red[4 + w] = s2;
    __syncthreads();
    const float var = (red[4] + red[5] + red[6] + red[7]) * (1.f / 1024.f);
    const float rs = rsqrtf(var + 1e-5f);
    const float4 gv = ((const float4*)g)[tid];
    const float4 bv = ((const float4*)b)[tid];
    u32 p0 = (u32)f2b(d0 * rs * gv.x + bv.x) | ((u32)f2b(d1 * rs * gv.y + bv.y) << 16);
    u32 p1 = (u32)f2b(d2 * rs * gv.z + bv.z) | ((u32)f2b(d3 * rs * gv.w + bv.w) << 16);
    ((uint2*)(out + (size_t)row * 1024))[tid] = make_uint2(p0, p1);
}

// ---------------------------------------------------------------------------
extern "C" void kernel_launch(void* const* d_in, const int* in_sizes, int n_in,
                              void* d_out, int out_size, void* d_ws, size_t ws_size,
                              hipStream_t stream)
{
    const int*   idx   = (const int*)  d_in[0];
    const float* embed = (const float*)d_in[1];
    const float* Wq    = (const float*)d_in[2];
    const float* Wk    = (const float*)d_in[3];
    const float* Wv    = (const float*)d_in[4];
    const float* Wo    = (const float*)d_in[5];
    const float* bq    = (const float*)d_in[6];
    const float* bk    = (const float*)d_in[7];
    const float* bv    = (const float*)d_in[8];
    const float* bo    = (const float*)d_in[9];
    const float* ln1g  = (const float*)d_in[10];
    const float* ln1b  = (const float*)d_in[11];
    const float* ln2g  = (const float*)d_in[12];
    const float* ln2b  = (const float*)d_in[13];
    const float* w1    = (const float*)d_in[14];
    const float* b1    = (const float*)d_in[15];
    const float* w2    = (const float*)d_in[16];
    const float* b2    = (const float*)d_in[17];
    const float* lnfg  = (const float*)d_in[18];
    const float* lnfb  = (const float*)d_in[19];
    const float* headw = (const float*)d_in[20];

    char* ws = (char*)d_ws;
    auto alloc = [&](size_t bytes) {
        char* p = ws;
        ws += (bytes + 255) & ~(size_t)255;
        return p;
    };
    u16*   qkvT = (u16*)alloc((size_t)4 * 3072 * 1024 * 2);
    u16*   WoT  = (u16*)alloc((size_t)4 * 1024 * 1024 * 2);
    u16*   w1T  = (u16*)alloc((size_t)4 * 1024 * 4096 * 2);
    u16*   w2T  = (u16*)alloc((size_t)4 * 1024 * 4096 * 2);
    u16*   hT   = (u16*)alloc((size_t)32000 * 1024 * 2);
    float* bcat = (float*)alloc((size_t)4 * 3072 * 4);
    float* x    = (float*)alloc((size_t)2048 * 1024 * 4);
    u16*   hb   = (u16*)alloc((size_t)2048 * 1024 * 2);
    u16*   qkvb = (u16*)alloc((size_t)2048 * 3072 * 2);
    u16*   vTb  = (u16*)alloc((size_t)2048 * 1024 * 2);
    u16*   ab   = (u16*)alloc((size_t)2048 * 1024 * 2);
    u16*   ff   = (u16*)alloc((size_t)2048 * 4096 * 2);
    float* pbuf = (float*)d_out;   // split-K partials; head GEMM overwrites at the end

    transpose_cvt_k<<<dim3(32, 32, 4),  256, 0, stream>>>(Wq, qkvT,            1024, 1024, 1048576, 3145728);
    transpose_cvt_k<<<dim3(32, 32, 4),  256, 0, stream>>>(Wk, qkvT + 1048576,  1024, 1024, 1048576, 3145728);
    transpose_cvt_k<<<dim3(32, 32, 4),  256, 0, stream>>>(Wv, qkvT + 2097152,  1024, 1024, 1048576, 3145728);
    transpose_cvt_k<<<dim3(32, 32, 4),  256, 0, stream>>>(Wo, WoT,             1024, 1024, 1048576, 1048576);
    transpose_cvt_k<<<dim3(128, 32, 4), 256, 0, stream>>>(w1, w1T,             1024, 4096, 4194304, 4194304);
    transpose_cvt_k<<<dim3(32, 128, 4), 256, 0, stream>>>(w2, w2T,             4096, 1024, 4194304, 4194304);
    transpose_cvt_k<<<dim3(1000, 32, 1), 256, 0, stream>>>(headw, hT,          1024, 32000, 0, 0);
    concat_bias_k<<<dim3(12, 4), 256, 0, stream>>>(bq, bk, bv, bcat);

    embed_pos_k<<<dim3(2048), 256, 0, stream>>>(idx, embed, x);
    layernorm_k<<<dim3(2048), 256, 0, stream>>>(x, ln1g, ln1b, hb);

    for (int l = 0; l < 4; ++l) {
        // qkv: 128^2 deep, N=3072, 384 blocks
        gemm_deep_k<128, 1024, 0><<<dim3(384), 256, 0, stream>>>(
            hb, 1024, qkvT + (size_t)l * 3145728, 1024,
            bcat + l * 3072, nullptr, qkvb, 3072, 16, 0, 0);
        transpose_u16_k<<<dim3(32, 64), 256, 0, stream>>>(qkvb + 2048, vTb, 2048, 1024, 3072);
        flash_attn_k<<<dim3(32, 16), 256, 0, stream>>>(qkvb, vTb, ab);
        // o-proj: split-K=2 (KC=512), 128x2 blocks
        gemm_deep_k<128, 512, 4><<<dim3(128, 2), 256, 0, stream>>>(
            ab, 1024, WoT + (size_t)l * 1048576, 1024,
            nullptr, pbuf, nullptr, 1024, 16, 512, 2097152);
        reduce_ln_k<<<dim3(2048), 256, 0, stream>>>(pbuf, 2, bo + l * 1024, x,
                                                    ln2g + l * 1024, ln2b + l * 1024, hb);
        // ffn1: gelu, N=4096, 512 blocks
        gemm_deep_k<128, 1024, 1><<<dim3(512), 256, 0, stream>>>(
            hb, 1024, w1T + (size_t)l * 4194304, 1024,
            b1 + l * 4096, nullptr, ff, 4096, 16, 0, 0);
        // ffn2: split-K=4 (KC=1024 of 4096), 128x4 blocks
        gemm_deep_k<128, 1024, 4><<<dim3(128, 4), 256, 0, stream>>>(
            ff, 4096, w2T + (size_t)l * 4194304, 4096,
            nullptr, pbuf, nullptr, 1024, 16, 1024, 2097152);
        const float* ng = (l < 3) ? (ln1g + (l + 1) * 1024) : lnfg;
        const float* nb = (l < 3) ? (ln1b + (l + 1) * 1024) : lnfb;
        reduce_ln_k<<<dim3(2048), 256, 0, stream>>>(pbuf, 4, b2 + l * 1024, x, ng, nb, hb);
    }
    // head: 256^2 deep, grid 8x125 = 1000 blocks of 512
    gemm_deep_k<256, 1024, 3><<<dim3(1000), 512, 0, stream>>>(
        hb, 1024, hT, 1024, nullptr, (float*)d_out, nullptr, 32000, 8, 0, 0);
}